// Round 2
// baseline (780.618 us; speedup 1.0000x reference)
//
#include <hip/hip_runtime.h>
#include <math.h>

#define P_TOT 65536   // 16*64*64 spatial positions
#define CH    128     // channels
#define NHEAD 8
#define KD    4
#define KH    8
#define KW    8
#define NJ    256     // KD*KH*KW keys per head

// ---------------- LayerNorm over channel axis, per position ----------------
__global__ __launch_bounds__(256) void k_ln(const float* __restrict__ x,
                                            const float* __restrict__ g,
                                            const float* __restrict__ b,
                                            float* __restrict__ xn) {
    int p = blockIdx.x * 256 + threadIdx.x;
    float sum = 0.f, ssq = 0.f;
    for (int c = 0; c < CH; ++c) {
        float v = x[c * P_TOT + p];
        sum += v; ssq += v * v;
    }
    float mean = sum * (1.f / CH);
    float var  = ssq * (1.f / CH) - mean * mean;
    float inv  = 1.f / sqrtf(var + 1e-5f);
    for (int c = 0; c < CH; ++c) {
        float v = x[c * P_TOT + p];
        xn[c * P_TOT + p] = (v - mean) * inv * g[c] + b[c];
    }
}

// ---------------- fp32 GEMM: C[M x 65536] = A[M x K] @ B[K x 65536] (+bias) ----
// block tile 128o x 128p, k-chunk 32, 8x8 microtile, 256 threads
__global__ __launch_bounds__(256) void k_gemm(const float* __restrict__ A, int lda, int K,
                                              const float* __restrict__ B,
                                              float* __restrict__ Cg,
                                              const float* __restrict__ bias) {
    __shared__ float a_lds[128 * 33];
    __shared__ float b_lds[32 * 129];
    int t  = threadIdx.x;
    int tx = t & 15, ty = t >> 4;
    int p0 = blockIdx.x * 128;
    int o0 = blockIdx.y * 128;
    float acc[8][8] = {};
    for (int k0 = 0; k0 < K; k0 += 32) {
        #pragma unroll
        for (int r = 0; r < 16; ++r) {          // stage A 128x32
            int idx = t + 256 * r;
            int o = idx >> 5, kc = idx & 31;
            a_lds[o * 33 + kc] = A[(o0 + o) * lda + k0 + kc];
        }
        #pragma unroll
        for (int r = 0; r < 16; ++r) {          // stage B 32x128
            int idx = t + 256 * r;
            int pp = idx & 127, kc = idx >> 7;
            b_lds[kc * 129 + pp] = B[(k0 + kc) * P_TOT + p0 + pp];
        }
        __syncthreads();
        for (int kc = 0; kc < 32; ++kc) {
            float af[8], bf[8];
            #pragma unroll
            for (int i = 0; i < 8; ++i) af[i] = a_lds[(ty * 8 + i) * 33 + kc];
            #pragma unroll
            for (int j = 0; j < 8; ++j) bf[j] = b_lds[kc * 129 + tx + 16 * j];
            #pragma unroll
            for (int i = 0; i < 8; ++i)
                #pragma unroll
                for (int j = 0; j < 8; ++j)
                    acc[i][j] += af[i] * bf[j];
        }
        __syncthreads();
    }
    #pragma unroll
    for (int i = 0; i < 8; ++i) {
        int o = o0 + ty * 8 + i;
        float bv = bias ? bias[o] : 0.f;
        #pragma unroll
        for (int j = 0; j < 8; ++j)
            Cg[o * P_TOT + p0 + tx + 16 * j] = acc[i][j] + bv;
    }
}

// ---------------- l2-normalize q,k rows in place (per head, per position) ----
__global__ __launch_bounds__(256) void k_norm(float* __restrict__ qk) {
    int p = blockIdx.x * 256 + threadIdx.x;
    for (int grp = 0; grp < 16; ++grp) {   // 8 q-heads then 8 k-heads
        float v[32]; float ssq = 0.f;
        #pragma unroll
        for (int c = 0; c < 32; ++c) {
            v[c] = qk[(grp * 32 + c) * P_TOT + p];
            ssq += v[c] * v[c];
        }
        float n  = sqrtf(ssq);
        float sc = 1.f / fmaxf(n, 1e-12f);
        #pragma unroll
        for (int c = 0; c < 32; ++c)
            qk[(grp * 32 + c) * P_TOT + p] = v[c] * sc;
    }
}

// ---------------- probes: per (row o, d): total, per-h sums, per-w sums ------
__global__ __launch_bounds__(256) void k_probe(const float* __restrict__ qk,
                                               float* __restrict__ pd,
                                               float* __restrict__ pdh,
                                               float* __restrict__ pdw) {
    int o = blockIdx.x;   // 0..511
    int d = blockIdx.y;   // 0..15
    int t = threadIdx.x;
    __shared__ float ph2[64 * 65];
    __shared__ float pwl[256];
    for (int i = t; i < 64 * 65; i += 256) ph2[i] = 0.f;
    __syncthreads();
    const float* src = qk + o * P_TOT + d * 4096;
    int col = t & 63;
    int tg  = t >> 6;
    float wsum = 0.f;
    #pragma unroll
    for (int r = 0; r < 16; ++r) {
        int i = t + 256 * r;
        float val = fabsf(src[i]);
        wsum += val;
        int h = 4 * r + tg;                // wave-uniform h, unique (h,col) per thread
        ph2[h * 65 + col] += val;
    }
    pwl[t] = wsum;
    __syncthreads();
    if (t < 64) {
        float s = 0.f;
        for (int cc = 0; cc < 64; ++cc) s += ph2[t * 65 + cc];
        pdh[(o * 16 + d) * 64 + t] = s;
        ph2[t * 65 + 64] = s;
    } else if (t < 128) {
        int w = t - 64;
        float s = 0.f;
        for (int g2 = 0; g2 < 4; ++g2) s += pwl[g2 * 64 + w];
        pdw[(o * 16 + d) * 64 + w] = s;
    }
    __syncthreads();
    if (t == 0) {
        float s = 0.f;
        for (int h = 0; h < 64; ++h) s += ph2[h * 65 + 64];
        pd[o * 16 + d] = s;
    }
}

// ---------------- top-k kernels (tie-break: lowest index, matches lax.top_k) --
__global__ __launch_bounds__(64) void k_topk_d(const float* __restrict__ pd,
                                               int* __restrict__ idx_d) {
    int h = blockIdx.x, t = threadIdx.x;
    __shared__ float sc[16];
    if (t < 16) {
        float s = 0.f;
        for (int c = 0; c < 32; ++c)
            s += pd[(h * 32 + c) * 16 + t] * pd[(256 + h * 32 + c) * 16 + t];
        sc[t] = s;
    }
    __syncthreads();
    if (t == 0) {
        bool used[16] = {};
        for (int r = 0; r < KD; ++r) {
            int best = 0; float bv = -1e30f;
            for (int i = 0; i < 16; ++i)
                if (!used[i] && sc[i] > bv) { bv = sc[i]; best = i; }
            used[best] = true;
            idx_d[h * KD + r] = best;
        }
    }
}

__global__ __launch_bounds__(64) void k_topk_h(const float* __restrict__ pdh,
                                               const int* __restrict__ idx_d,
                                               int* __restrict__ idx_h) {
    int h = blockIdx.x, t = threadIdx.x; // t = h-index 0..63
    __shared__ float sc[64];
    int ds[KD];
    for (int i = 0; i < KD; ++i) ds[i] = idx_d[h * KD + i];
    float s = 0.f;
    for (int c = 0; c < 32; ++c) {
        int oq = h * 32 + c, ok = 256 + h * 32 + c;
        float qp = 0.f;
        for (int d = 0; d < 16; ++d) qp += pdh[(oq * 16 + d) * 64 + t];
        float kp = 0.f;
        for (int i = 0; i < KD; ++i) kp += pdh[(ok * 16 + ds[i]) * 64 + t];
        s += qp * kp;
    }
    sc[t] = s;
    __syncthreads();
    if (t == 0) {
        bool used[64] = {};
        for (int r = 0; r < KH; ++r) {
            int best = 0; float bv = -1e30f;
            for (int i = 0; i < 64; ++i)
                if (!used[i] && sc[i] > bv) { bv = sc[i]; best = i; }
            used[best] = true;
            idx_h[h * KH + r] = best;
        }
    }
}

__global__ __launch_bounds__(64) void k_probe_w(const float* __restrict__ qk,
                                                const int* __restrict__ idx_d,
                                                const int* __restrict__ idx_h,
                                                float* __restrict__ kpw) {
    int o2 = blockIdx.x;      // 0..255 k-row
    int w  = threadIdx.x;     // 0..63
    int h  = o2 >> 5;
    const float* src = qk + (256 + o2) * P_TOT;
    float s = 0.f;
    for (int i = 0; i < KD; ++i) {
        int pb = idx_d[h * KD + i] * 4096;
        for (int j = 0; j < KH; ++j)
            s += fabsf(src[pb + idx_h[h * KH + j] * 64 + w]);
    }
    kpw[o2 * 64 + w] = s;
}

__global__ __launch_bounds__(64) void k_topk_w(const float* __restrict__ pdw,
                                               const float* __restrict__ kpw,
                                               int* __restrict__ idx_w) {
    int h = blockIdx.x, t = threadIdx.x; // t = w-index 0..63
    __shared__ float sc[64];
    float s = 0.f;
    for (int c = 0; c < 32; ++c) {
        int oq = h * 32 + c;
        float qp = 0.f;
        for (int d = 0; d < 16; ++d) qp += pdw[(oq * 16 + d) * 64 + t];
        s += qp * kpw[(h * 32 + c) * 64 + t];
    }
    sc[t] = s;
    __syncthreads();
    if (t == 0) {
        bool used[64] = {};
        for (int r = 0; r < KW; ++r) {
            int best = 0; float bv = -1e30f;
            for (int i = 0; i < 64; ++i)
                if (!used[i] && sc[i] > bv) { bv = sc[i]; best = i; }
            used[best] = true;
            idx_w[h * KW + r] = best;
        }
    }
}

// ------- gather pruned k (normalized) and recompute v at selected positions ---
__global__ __launch_bounds__(64) void k_gather(const float* __restrict__ qk,
                                               const float* __restrict__ xn,
                                               const float* __restrict__ wqkv,
                                               const int* __restrict__ idx_d,
                                               const int* __restrict__ idx_h,
                                               const int* __restrict__ idx_w,
                                               float* __restrict__ k_sel,
                                               float* __restrict__ v_sel) {
    int h  = blockIdx.x;          // 0..7
    int jb = blockIdx.y;          // 0..127
    int t  = threadIdx.x;         // 0..63
    int j  = jb * 2 + (t >> 5);
    int c  = t & 31;
    int di = j >> 6, hi = (j >> 3) & 7, wi = j & 7;
    int p  = idx_d[h * KD + di] * 4096 + idx_h[h * KH + hi] * 64 + idx_w[h * KW + wi];
    k_sel[(h * NJ + j) * 32 + c] = qk[(256 + h * 32 + c) * P_TOT + p];
    const float* wr = wqkv + (512 + h * 32 + c) * CH;
    float acc = 0.f;
    for (int cc = 0; cc < CH; ++cc) acc += wr[cc] * xn[cc * P_TOT + p];
    v_sel[(h * NJ + j) * 32 + c] = acc;
}

// ------- attention: per-thread streaming softmax (|sim|<=1 -> no max sub) -----
// NOTE: reference reshapes (head, query, chan) -> (head, chan', pos') WITHOUT
// transpose: f = p*32+c maps to chan' = p>>11, pos' = (p&2047)*32+c. We must
// write the scrambled layout since the final projection consumes it.
__global__ __launch_bounds__(256) void k_attn(const float* __restrict__ qk,
                                              const float* __restrict__ k_sel,
                                              const float* __restrict__ v_sel,
                                              float* __restrict__ attn) {
    int h  = blockIdx.x >> 8;
    int pb = blockIdx.x & 255;
    int p  = pb * 256 + threadIdx.x;
    float qv[32];
    #pragma unroll
    for (int c = 0; c < 32; ++c) qv[c] = qk[(h * 32 + c) * P_TOT + p];
    float acc[32] = {};
    float den = 0.f;
    const float4* ks = (const float4*)(k_sel + h * NJ * 32);
    const float4* vs = (const float4*)(v_sel + h * NJ * 32);
    for (int j = 0; j < NJ; ++j) {
        float s = 0.f;
        #pragma unroll
        for (int c8 = 0; c8 < 8; ++c8) {
            float4 kk = ks[j * 8 + c8];
            s += qv[c8*4+0]*kk.x + qv[c8*4+1]*kk.y + qv[c8*4+2]*kk.z + qv[c8*4+3]*kk.w;
        }
        float e = __expf(s);
        den += e;
        #pragma unroll
        for (int c8 = 0; c8 < 8; ++c8) {
            float4 vv = vs[j * 8 + c8];
            acc[c8*4+0] += e*vv.x; acc[c8*4+1] += e*vv.y;
            acc[c8*4+2] += e*vv.z; acc[c8*4+3] += e*vv.w;
        }
    }
    float inv = 1.f / den;
    // scrambled write: chan' = h*32 + (p>>11), pos' = (p&2047)*32 + c
    float4* dst = (float4*)(attn + ((size_t)(h * 32 + (p >> 11))) * P_TOT
                                 + (p & 2047) * 32);
    #pragma unroll
    for (int c8 = 0; c8 < 8; ++c8) {
        float4 o;
        o.x = acc[c8*4+0] * inv; o.y = acc[c8*4+1] * inv;
        o.z = acc[c8*4+2] * inv; o.w = acc[c8*4+3] * inv;
        dst[c8] = o;
    }
}

extern "C" void kernel_launch(void* const* d_in, const int* in_sizes, int n_in,
                              void* d_out, int out_size, void* d_ws, size_t ws_size,
                              hipStream_t stream) {
    const float* x    = (const float*)d_in[0];
    const float* g    = (const float*)d_in[1];
    const float* b    = (const float*)d_in[2];
    const float* wqkv = (const float*)d_in[3];
    const float* wout = (const float*)d_in[4];
    const float* bout = (const float*)d_in[5];
    float* out = (float*)d_out;
    float* ws  = (float*)d_ws;

    // ws layout (floats):
    float* xn   = ws;                       // 128*65536            = 8,388,608
    float* qk   = ws + 8388608;             // 512*65536 rows: q[0..255], k[256..511]
    float* attn = qk + 256 * P_TOT;         // overlays k rows after gather
    float* aux  = ws + 41943040;
    float* pd    = aux;                     // 512*16
    float* pdh   = pd + 8192;               // 512*16*64
    float* pdw   = pdh + 524288;            // 512*16*64
    float* kpw   = pdw + 524288;            // 256*64
    float* k_sel = kpw + 16384;             // 8*256*32
    float* v_sel = k_sel + 65536;           // 8*256*32
    int*   idx_d = (int*)(v_sel + 65536);   // 8*4
    int*   idx_h = idx_d + 32;              // 8*8
    int*   idx_w = idx_h + 64;              // 8*8

    k_ln<<<256, 256, 0, stream>>>(x, g, b, xn);
    k_gemm<<<dim3(512, 4), 256, 0, stream>>>(wqkv, CH, CH, xn, qk, (const float*)nullptr);
    k_norm<<<256, 256, 0, stream>>>(qk);
    k_probe<<<dim3(512, 16), 256, 0, stream>>>(qk, pd, pdh, pdw);
    k_topk_d<<<8, 64, 0, stream>>>(pd, idx_d);
    k_topk_h<<<8, 64, 0, stream>>>(pdh, idx_d, idx_h);
    k_probe_w<<<256, 64, 0, stream>>>(qk, idx_d, idx_h, kpw);
    k_topk_w<<<8, 64, 0, stream>>>(pdw, kpw, idx_w);
    k_gather<<<dim3(8, 128), 64, 0, stream>>>(qk, xn, wqkv, idx_d, idx_h, idx_w, k_sel, v_sel);
    k_attn<<<2048, 256, 0, stream>>>(qk, k_sel, v_sel, attn);
    k_gemm<<<dim3(512, 1), 256, 0, stream>>>(wout, 256, 256, attn, out, bout);
}

// Round 3
// 658.893 us; speedup vs baseline: 1.1847x; 1.1847x over previous
//
#include <hip/hip_runtime.h>
#include <math.h>

#define P_TOT 65536   // 16*64*64 spatial positions
#define CH    128     // channels
#define NHEAD 8
#define KD    4
#define KH    8
#define KW    8
#define NJ    256     // KD*KH*KW keys per head

typedef unsigned short u16;
typedef unsigned int   u32;
typedef __attribute__((ext_vector_type(8))) short frag8;   // bf16x8 (4 VGPRs)
typedef __attribute__((ext_vector_type(4))) float f32x4;   // MFMA C/D

__device__ inline u32 bf16pair(float a, float b) {         // RTNE pack (lo=a, hi=b)
    u32 ua = __float_as_uint(a), ub = __float_as_uint(b);
    ua = (ua + 0x7fff + ((ua >> 16) & 1)) >> 16;
    ub = (ub + 0x7fff + ((ub >> 16) & 1)) & 0xffff0000u;
    return ua | ub;
}
__device__ inline u16 bf16r(float a) {
    u32 ua = __float_as_uint(a);
    return (u16)((ua + 0x7fff + ((ua >> 16) & 1)) >> 16);
}

// ---------------- LayerNorm over channel axis, per position ----------------
__global__ __launch_bounds__(256) void k_ln(const float* __restrict__ x,
                                            const float* __restrict__ g,
                                            const float* __restrict__ b,
                                            float* __restrict__ xn) {
    int p = blockIdx.x * 256 + threadIdx.x;
    float sum = 0.f, ssq = 0.f;
    for (int c = 0; c < CH; ++c) {
        float v = x[c * P_TOT + p];
        sum += v; ssq += v * v;
    }
    float mean = sum * (1.f / CH);
    float var  = ssq * (1.f / CH) - mean * mean;
    float inv  = 1.f / sqrtf(var + 1e-5f);
    for (int c = 0; c < CH; ++c) {
        float v = x[c * P_TOT + p];
        xn[c * P_TOT + p] = (v - mean) * inv * g[c] + b[c];
    }
}

// ---------------- fp32 GEMM: C[M x 65536] = A[M x K] @ B[K x 65536] (+bias) ----
__global__ __launch_bounds__(256) void k_gemm(const float* __restrict__ A, int lda, int K,
                                              const float* __restrict__ B,
                                              float* __restrict__ Cg,
                                              const float* __restrict__ bias) {
    __shared__ float a_lds[128 * 33];
    __shared__ float b_lds[32 * 129];
    int t  = threadIdx.x;
    int tx = t & 15, ty = t >> 4;
    int p0 = blockIdx.x * 128;
    int o0 = blockIdx.y * 128;
    float acc[8][8] = {};
    for (int k0 = 0; k0 < K; k0 += 32) {
        #pragma unroll
        for (int r = 0; r < 16; ++r) {
            int idx = t + 256 * r;
            int o = idx >> 5, kc = idx & 31;
            a_lds[o * 33 + kc] = A[(o0 + o) * lda + k0 + kc];
        }
        #pragma unroll
        for (int r = 0; r < 16; ++r) {
            int idx = t + 256 * r;
            int pp = idx & 127, kc = idx >> 7;
            b_lds[kc * 129 + pp] = B[(k0 + kc) * P_TOT + p0 + pp];
        }
        __syncthreads();
        for (int kc = 0; kc < 32; ++kc) {
            float af[8], bf[8];
            #pragma unroll
            for (int i = 0; i < 8; ++i) af[i] = a_lds[(ty * 8 + i) * 33 + kc];
            #pragma unroll
            for (int j = 0; j < 8; ++j) bf[j] = b_lds[kc * 129 + tx + 16 * j];
            #pragma unroll
            for (int i = 0; i < 8; ++i)
                #pragma unroll
                for (int j = 0; j < 8; ++j)
                    acc[i][j] += af[i] * bf[j];
        }
        __syncthreads();
    }
    #pragma unroll
    for (int i = 0; i < 8; ++i) {
        int o = o0 + ty * 8 + i;
        float bv = bias ? bias[o] : 0.f;
        #pragma unroll
        for (int j = 0; j < 8; ++j)
            Cg[o * P_TOT + p0 + tx + 16 * j] = acc[i][j] + bv;
    }
}

// ------- l2-normalize q,k in place; additionally emit qT bf16 [h][p][32] -----
__global__ __launch_bounds__(256) void k_norm(float* __restrict__ qk,
                                              u16* __restrict__ qT) {
    int p = blockIdx.x * 256 + threadIdx.x;
    for (int grp = 0; grp < 16; ++grp) {   // 8 q-heads then 8 k-heads
        float v[32]; float ssq = 0.f;
        #pragma unroll
        for (int c = 0; c < 32; ++c) {
            v[c] = qk[(grp * 32 + c) * P_TOT + p];
            ssq += v[c] * v[c];
        }
        float n  = sqrtf(ssq);
        float sc = 1.f / fmaxf(n, 1e-12f);
        #pragma unroll
        for (int c = 0; c < 32; ++c) {
            v[c] *= sc;
            qk[(grp * 32 + c) * P_TOT + p] = v[c];
        }
        if (grp < 8) {
            u32* qrow = (u32*)(qT + ((size_t)grp * P_TOT + p) * 32);
            #pragma unroll
            for (int i = 0; i < 16; ++i)
                qrow[i] = bf16pair(v[2 * i], v[2 * i + 1]);
        }
    }
}

// ---------------- probes: per (row o, d): total, per-h sums, per-w sums ------
__global__ __launch_bounds__(256) void k_probe(const float* __restrict__ qk,
                                               float* __restrict__ pd,
                                               float* __restrict__ pdh,
                                               float* __restrict__ pdw) {
    int o = blockIdx.x;   // 0..511
    int d = blockIdx.y;   // 0..15
    int t = threadIdx.x;
    __shared__ float ph2[64 * 65];
    __shared__ float pwl[256];
    for (int i = t; i < 64 * 65; i += 256) ph2[i] = 0.f;
    __syncthreads();
    const float* src = qk + o * P_TOT + d * 4096;
    int col = t & 63;
    int tg  = t >> 6;
    float wsum = 0.f;
    #pragma unroll
    for (int r = 0; r < 16; ++r) {
        int i = t + 256 * r;
        float val = fabsf(src[i]);
        wsum += val;
        int h = 4 * r + tg;
        ph2[h * 65 + col] += val;
    }
    pwl[t] = wsum;
    __syncthreads();
    if (t < 64) {
        float s = 0.f;
        for (int cc = 0; cc < 64; ++cc) s += ph2[t * 65 + cc];
        pdh[(o * 16 + d) * 64 + t] = s;
        ph2[t * 65 + 64] = s;
    } else if (t < 128) {
        int w = t - 64;
        float s = 0.f;
        for (int g2 = 0; g2 < 4; ++g2) s += pwl[g2 * 64 + w];
        pdw[(o * 16 + d) * 64 + w] = s;
    }
    __syncthreads();
    if (t == 0) {
        float s = 0.f;
        for (int h = 0; h < 64; ++h) s += ph2[h * 65 + 64];
        pd[o * 16 + d] = s;
    }
}

// ---------------- top-k kernels ----------------
__global__ __launch_bounds__(64) void k_topk_d(const float* __restrict__ pd,
                                               int* __restrict__ idx_d) {
    int h = blockIdx.x, t = threadIdx.x;
    __shared__ float sc[16];
    if (t < 16) {
        float s = 0.f;
        for (int c = 0; c < 32; ++c)
            s += pd[(h * 32 + c) * 16 + t] * pd[(256 + h * 32 + c) * 16 + t];
        sc[t] = s;
    }
    __syncthreads();
    if (t == 0) {
        bool used[16] = {};
        for (int r = 0; r < KD; ++r) {
            int best = 0; float bv = -1e30f;
            for (int i = 0; i < 16; ++i)
                if (!used[i] && sc[i] > bv) { bv = sc[i]; best = i; }
            used[best] = true;
            idx_d[h * KD + r] = best;
        }
    }
}

__global__ __launch_bounds__(64) void k_topk_h(const float* __restrict__ pdh,
                                               const int* __restrict__ idx_d,
                                               int* __restrict__ idx_h) {
    int h = blockIdx.x, t = threadIdx.x;
    __shared__ float sc[64];
    int ds[KD];
    for (int i = 0; i < KD; ++i) ds[i] = idx_d[h * KD + i];
    float s = 0.f;
    for (int c = 0; c < 32; ++c) {
        int oq = h * 32 + c, ok = 256 + h * 32 + c;
        float qp = 0.f;
        for (int d = 0; d < 16; ++d) qp += pdh[(oq * 16 + d) * 64 + t];
        float kp = 0.f;
        for (int i = 0; i < KD; ++i) kp += pdh[(ok * 16 + ds[i]) * 64 + t];
        s += qp * kp;
    }
    sc[t] = s;
    __syncthreads();
    if (t == 0) {
        bool used[64] = {};
        for (int r = 0; r < KH; ++r) {
            int best = 0; float bv = -1e30f;
            for (int i = 0; i < 64; ++i)
                if (!used[i] && sc[i] > bv) { bv = sc[i]; best = i; }
            used[best] = true;
            idx_h[h * KH + r] = best;
        }
    }
}

__global__ __launch_bounds__(64) void k_probe_w(const float* __restrict__ qk,
                                                const int* __restrict__ idx_d,
                                                const int* __restrict__ idx_h,
                                                float* __restrict__ kpw) {
    int o2 = blockIdx.x;
    int w  = threadIdx.x;
    int h  = o2 >> 5;
    const float* src = qk + (256 + o2) * P_TOT;
    float s = 0.f;
    for (int i = 0; i < KD; ++i) {
        int pb = idx_d[h * KD + i] * 4096;
        for (int j = 0; j < KH; ++j)
            s += fabsf(src[pb + idx_h[h * KH + j] * 64 + w]);
    }
    kpw[o2 * 64 + w] = s;
}

__global__ __launch_bounds__(64) void k_topk_w(const float* __restrict__ pdw,
                                               const float* __restrict__ kpw,
                                               int* __restrict__ idx_w) {
    int h = blockIdx.x, t = threadIdx.x;
    __shared__ float sc[64];
    float s = 0.f;
    for (int c = 0; c < 32; ++c) {
        int oq = h * 32 + c;
        float qp = 0.f;
        for (int d = 0; d < 16; ++d) qp += pdw[(oq * 16 + d) * 64 + t];
        s += qp * kpw[(h * 32 + c) * 64 + t];
    }
    sc[t] = s;
    __syncthreads();
    if (t == 0) {
        bool used[64] = {};
        for (int r = 0; r < KW; ++r) {
            int best = 0; float bv = -1e30f;
            for (int i = 0; i < 64; ++i)
                if (!used[i] && sc[i] > bv) { bv = sc[i]; best = i; }
            used[best] = true;
            idx_w[h * KW + r] = best;
        }
    }
}

// ------- gather pruned k (bf16 [h][j][32]) + recompute v (bf16 [h][c][256]) ---
__global__ __launch_bounds__(64) void k_gather(const float* __restrict__ qk,
                                               const float* __restrict__ xn,
                                               const float* __restrict__ wqkv,
                                               const int* __restrict__ idx_d,
                                               const int* __restrict__ idx_h,
                                               const int* __restrict__ idx_w,
                                               u16* __restrict__ kb,
                                               u16* __restrict__ vT) {
    int h  = blockIdx.x;          // 0..7
    int jb = blockIdx.y;          // 0..127
    int t  = threadIdx.x;         // 0..63
    int j  = jb * 2 + (t >> 5);
    int c  = t & 31;
    int di = j >> 6, hi = (j >> 3) & 7, wi = j & 7;
    int p  = idx_d[h * KD + di] * 4096 + idx_h[h * KH + hi] * 64 + idx_w[h * KW + wi];
    kb[(h * NJ + j) * 32 + c] = bf16r(qk[(256 + h * 32 + c) * P_TOT + p]);
    const float* wr = wqkv + (512 + h * 32 + c) * CH;
    float acc = 0.f;
    for (int cc = 0; cc < CH; ++cc) acc += wr[cc] * xn[cc * P_TOT + p];
    vT[((size_t)h * 32 + c) * NJ + j] = bf16r(acc);
}

// ------- MFMA flash attention: one wave = 16 queries ------------------------
// S^T = K.Q^T via mfma_16x16x32_bf16 (A=K rows j, B=Q^T, D col=q=lane&15,
// row=j=quad*4+reg). exp -> den (lane sum + shfl_xor 16,32). P->bf16 LDS
// [q][j] (stride 264), PV: O^T = V^T.P^T (A=V^T from global, B=P^T from LDS).
// Output written in the reference's scrambled reshape layout (see R2 note).
__global__ __launch_bounds__(256) void k_attn(const u16* __restrict__ qT,
                                              const u16* __restrict__ kb,
                                              const u16* __restrict__ vT,
                                              float* __restrict__ attn) {
    __shared__ u16 sP[4 * 16 * 264];
    int h    = blockIdx.x >> 10;
    int pb   = blockIdx.x & 1023;
    int wave = threadIdx.x >> 6;
    int lane = threadIdx.x & 63;
    int m    = lane & 15;
    int quad = lane >> 4;
    u16* sPw = sP + wave * (16 * 264);

    int q0 = pb * 64 + wave * 16;
    int p  = q0 + m;

    frag8 bq = *(const frag8*)(qT + ((size_t)h * P_TOT + p) * 32 + quad * 8);
    const u16* kbase = kb + (size_t)h * NJ * 32;

    f32x4 zero = {0.f, 0.f, 0.f, 0.f};
    float den = 0.f;
    #pragma unroll
    for (int t = 0; t < 16; ++t) {
        frag8 ak = *(const frag8*)(kbase + (t * 16 + m) * 32 + quad * 8);
        f32x4 st = __builtin_amdgcn_mfma_f32_16x16x32_bf16(ak, bq, zero, 0, 0, 0);
        float e0 = __expf(st[0]);
        float e1 = __expf(st[1]);
        float e2 = __expf(st[2]);
        float e3 = __expf(st[3]);
        den += (e0 + e1) + (e2 + e3);
        u32* dst = (u32*)(sPw + m * 264 + t * 16 + quad * 4);
        dst[0] = bf16pair(e0, e1);
        dst[1] = bf16pair(e2, e3);
    }
    den += __shfl_xor(den, 16, 64);
    den += __shfl_xor(den, 32, 64);
    __syncthreads();   // LDS write->read safety (per-wave region, cross-lane)

    const u16* vbase = vT + (size_t)h * 32 * NJ;
    f32x4 acc0 = {0.f, 0.f, 0.f, 0.f}, acc1 = {0.f, 0.f, 0.f, 0.f};
    #pragma unroll
    for (int jc = 0; jc < 8; ++jc) {
        frag8 bp  = *(const frag8*)(sPw + m * 264 + jc * 32 + quad * 8);
        frag8 av0 = *(const frag8*)(vbase + (size_t)m * NJ + jc * 32 + quad * 8);
        frag8 av1 = *(const frag8*)(vbase + (size_t)(16 + m) * NJ + jc * 32 + quad * 8);
        acc0 = __builtin_amdgcn_mfma_f32_16x16x32_bf16(av0, bp, acc0, 0, 0, 0);
        acc1 = __builtin_amdgcn_mfma_f32_16x16x32_bf16(av1, bp, acc1, 0, 0, 0);
    }
    float inv = 1.f / den;
    size_t base = ((size_t)(h * 32 + (p >> 11))) * P_TOT + (size_t)(p & 2047) * 32;
    float4 o0, o1;
    o0.x = acc0[0] * inv; o0.y = acc0[1] * inv; o0.z = acc0[2] * inv; o0.w = acc0[3] * inv;
    o1.x = acc1[0] * inv; o1.y = acc1[1] * inv; o1.z = acc1[2] * inv; o1.w = acc1[3] * inv;
    *(float4*)(attn + base + quad * 4)      = o0;
    *(float4*)(attn + base + 16 + quad * 4) = o1;
}

extern "C" void kernel_launch(void* const* d_in, const int* in_sizes, int n_in,
                              void* d_out, int out_size, void* d_ws, size_t ws_size,
                              hipStream_t stream) {
    const float* x    = (const float*)d_in[0];
    const float* g    = (const float*)d_in[1];
    const float* b    = (const float*)d_in[2];
    const float* wqkv = (const float*)d_in[3];
    const float* wout = (const float*)d_in[4];
    const float* bout = (const float*)d_in[5];
    float* out = (float*)d_out;
    float* ws  = (float*)d_ws;

    // ws layout (floats unless noted):
    float* xn   = ws;                       // 8,388,608
    float* qk   = ws + 8388608;             // 512*65536 (q rows 0..255, k rows 256..511)
    float* attn = qk + 256 * P_TOT;         // overlays k rows after gather
    float* aux  = ws + 41943040;
    float* pd    = aux;                     // 8192
    float* pdh   = pd + 8192;               // 524288
    float* pdw   = pdh + 524288;            // 524288
    float* kpw   = pdw + 524288;            // 16384
    int*   idx_d = (int*)(kpw + 16384);     // 32
    int*   idx_h = idx_d + 32;              // 64
    int*   idx_w = idx_h + 64;              // 64
    u16*   kb    = (u16*)(idx_w + 64);      // 8*256*32 bf16
    u16*   vT    = kb + 8 * NJ * 32;        // 8*32*256 bf16
    u16*   qT    = vT + 8 * 32 * NJ;        // 8*65536*32 bf16 (33.5 MB)

    k_ln<<<256, 256, 0, stream>>>(x, g, b, xn);
    k_gemm<<<dim3(512, 4), 256, 0, stream>>>(wqkv, CH, CH, xn, qk, (const float*)nullptr);
    k_norm<<<256, 256, 0, stream>>>(qk, qT);
    k_probe<<<dim3(512, 16), 256, 0, stream>>>(qk, pd, pdh, pdw);
    k_topk_d<<<8, 64, 0, stream>>>(pd, idx_d);
    k_topk_h<<<8, 64, 0, stream>>>(pdh, idx_d, idx_h);
    k_probe_w<<<256, 64, 0, stream>>>(qk, idx_d, idx_h, kpw);
    k_topk_w<<<8, 64, 0, stream>>>(pdw, kpw, idx_w);
    k_gather<<<dim3(8, 128), 64, 0, stream>>>(qk, xn, wqkv, idx_d, idx_h, idx_w, kb, vT);
    k_attn<<<8192, 256, 0, stream>>>(qT, kb, vT, attn);
    k_gemm<<<dim3(512, 1), 256, 0, stream>>>(wout, 256, 256, attn, out, bout);
}

// Round 4
// 640.652 us; speedup vs baseline: 1.2185x; 1.0285x over previous
//
#include <hip/hip_runtime.h>
#include <math.h>

#define P_TOT 65536   // 16*64*64 spatial positions
#define CH    128     // channels
#define NHEAD 8
#define KD    4
#define KH    8
#define KW    8
#define NJ    256     // KD*KH*KW keys per head

typedef unsigned short u16;
typedef unsigned int   u32;
typedef __attribute__((ext_vector_type(8))) short frag8;   // bf16x8 (4 VGPRs)
typedef __attribute__((ext_vector_type(4))) float f32x4;   // MFMA C/D

__device__ inline u32 bf16pair(float a, float b) {         // RTNE pack (lo=a, hi=b)
    u32 ua = __float_as_uint(a), ub = __float_as_uint(b);
    ua = (ua + 0x7fff + ((ua >> 16) & 1)) >> 16;
    ub = (ub + 0x7fff + ((ub >> 16) & 1)) & 0xffff0000u;
    return ua | ub;
}
__device__ inline u16 bf16r(float a) {
    u32 ua = __float_as_uint(a);
    return (u16)((ua + 0x7fff + ((ua >> 16) & 1)) >> 16);
}
__device__ inline float bf16f(u16 h) {
    return __uint_as_float(((u32)h) << 16);
}

// ------- LayerNorm; emits TRANSPOSED bf16 hi/lo planes xnT[p][c] ------------
// hi = bf16(xn), lo = bf16(xn - hi): xn reconstructed to ~2^-17 rel error.
__global__ __launch_bounds__(256) void k_ln(const float* __restrict__ x,
                                            const float* __restrict__ g,
                                            const float* __restrict__ b,
                                            u16* __restrict__ xnT_hi,
                                            u16* __restrict__ xnT_lo) {
    int p = blockIdx.x * 256 + threadIdx.x;
    float sum = 0.f, ssq = 0.f;
    for (int c = 0; c < CH; ++c) {
        float v = x[c * P_TOT + p];
        sum += v; ssq += v * v;
    }
    float mean = sum * (1.f / CH);
    float var  = ssq * (1.f / CH) - mean * mean;
    float inv  = 1.f / sqrtf(var + 1e-5f);
    for (int c8 = 0; c8 < 16; ++c8) {
        u16 h8[8], l8[8];
        #pragma unroll
        for (int e = 0; e < 8; ++e) {
            int c = c8 * 8 + e;
            float v  = x[c * P_TOT + p];
            float xn = (v - mean) * inv * g[c] + b[c];
            u16 hh = bf16r(xn);
            l8[e] = bf16r(xn - bf16f(hh));
            h8[e] = hh;
        }
        *(uint4*)(xnT_hi + (size_t)p * 128 + c8 * 8) = *(uint4*)h8;
        *(uint4*)(xnT_lo + (size_t)p * 128 + c8 * 8) = *(uint4*)l8;
    }
}

// ------- split first 512 rows of wqkv into bf16 hi/lo planes [o][k] ---------
__global__ __launch_bounds__(256) void k_wsplit(const float* __restrict__ wqkv,
                                                u16* __restrict__ w_hi,
                                                u16* __restrict__ w_lo) {
    int id = blockIdx.x * 256 + threadIdx.x;   // 0..65535 = o*128+k
    float v = wqkv[id];
    u16 hh = bf16r(v);
    w_hi[id] = hh;
    w_lo[id] = bf16r(v - bf16f(hh));
}

// ------- MFMA qkv GEMM: qk[o][p] = sum_k w[o][k]*xn[k][p], bf16x3 split -----
// A-operand = xnT rows (m=p, k contiguous), B-operand = w rows (n=o).
// D: col=lane&15=o, row=quad*4+reg=p -> coalesced dwordx4 stores to qk.
// 3 passes: (A_hi,B_hi), (A_hi,B_lo), (A_lo,B_hi); K=128 each, BK=64.
// LDS tiles 128x64 u16 with XOR-16B swizzle (granule g' = g ^ (row&7)).
__global__ __launch_bounds__(256) void k_gemm_qkv(const u16* __restrict__ xnT_hi,
                                                  const u16* __restrict__ xnT_lo,
                                                  const u16* __restrict__ w_hi,
                                                  const u16* __restrict__ w_lo,
                                                  float* __restrict__ qk) {
    __shared__ u16 a_lds[128 * 64];
    __shared__ u16 b_lds[128 * 64];
    int t    = threadIdx.x;
    int lane = t & 63, wave = t >> 6;
    int wp = wave & 1, wo = wave >> 1;
    int m = lane & 15, quad = lane >> 4;
    int p0 = blockIdx.x * 128;
    int o0 = blockIdx.y * 128;
    f32x4 acc[4][4] = {};
    const u16* Asrc[3] = { xnT_hi, xnT_hi, xnT_lo };
    const u16* Bsrc[3] = { w_hi,   w_lo,   w_hi   };
    for (int pass = 0; pass < 3; ++pass) {
        const u16* Ap = Asrc[pass];
        const u16* Bp = Bsrc[pass];
        for (int half = 0; half < 2; ++half) {
            int k0 = half * 64;
            __syncthreads();                    // LDS reuse: readers done
            #pragma unroll
            for (int r2 = 0; r2 < 4; ++r2) {    // stage A+B (16 KB each)
                int id  = t + 256 * r2;         // 0..1023 granules of 16 B
                int row = id >> 3, gg = id & 7;
                int go  = (gg ^ (row & 7)) * 8;
                uint4 va = *(const uint4*)(Ap + (size_t)(p0 + row) * 128 + k0 + gg * 8);
                *(uint4*)(a_lds + row * 64 + go) = va;
                uint4 vb = *(const uint4*)(Bp + (size_t)(o0 + row) * 128 + k0 + gg * 8);
                *(uint4*)(b_lds + row * 64 + go) = vb;
            }
            __syncthreads();
            #pragma unroll
            for (int ks = 0; ks < 2; ++ks) {
                frag8 af[4], bf[4];
                #pragma unroll
                for (int i = 0; i < 4; ++i) {
                    int row = wp * 64 + i * 16 + m;
                    int gg  = (ks * 4 + quad) ^ (row & 7);
                    af[i] = *(const frag8*)(a_lds + row * 64 + gg * 8);
                }
                #pragma unroll
                for (int j = 0; j < 4; ++j) {
                    int row = wo * 64 + j * 16 + m;
                    int gg  = (ks * 4 + quad) ^ (row & 7);
                    bf[j] = *(const frag8*)(b_lds + row * 64 + gg * 8);
                }
                #pragma unroll
                for (int i = 0; i < 4; ++i)
                    #pragma unroll
                    for (int j = 0; j < 4; ++j)
                        acc[i][j] = __builtin_amdgcn_mfma_f32_16x16x32_bf16(
                            af[i], bf[j], acc[i][j], 0, 0, 0);
            }
        }
    }
    #pragma unroll
    for (int i = 0; i < 4; ++i) {
        int p = p0 + wp * 64 + i * 16 + quad * 4;
        #pragma unroll
        for (int j = 0; j < 4; ++j) {
            int o = o0 + wo * 64 + j * 16 + m;
            float4 v;
            v.x = acc[i][j][0]; v.y = acc[i][j][1];
            v.z = acc[i][j][2]; v.w = acc[i][j][3];
            *(float4*)(qk + (size_t)o * P_TOT + p) = v;
        }
    }
}

// ---------------- fp32 GEMM (kept for the output projection) ----------------
__global__ __launch_bounds__(256) void k_gemm(const float* __restrict__ A, int lda, int K,
                                              const float* __restrict__ B,
                                              float* __restrict__ Cg,
                                              const float* __restrict__ bias) {
    __shared__ float a_lds[128 * 33];
    __shared__ float b_lds[32 * 129];
    int t  = threadIdx.x;
    int tx = t & 15, ty = t >> 4;
    int p0 = blockIdx.x * 128;
    int o0 = blockIdx.y * 128;
    float acc[8][8] = {};
    for (int k0 = 0; k0 < K; k0 += 32) {
        #pragma unroll
        for (int r = 0; r < 16; ++r) {
            int idx = t + 256 * r;
            int o = idx >> 5, kc = idx & 31;
            a_lds[o * 33 + kc] = A[(o0 + o) * lda + k0 + kc];
        }
        #pragma unroll
        for (int r = 0; r < 16; ++r) {
            int idx = t + 256 * r;
            int pp = idx & 127, kc = idx >> 7;
            b_lds[kc * 129 + pp] = B[(k0 + kc) * P_TOT + p0 + pp];
        }
        __syncthreads();
        for (int kc = 0; kc < 32; ++kc) {
            float af[8], bf[8];
            #pragma unroll
            for (int i = 0; i < 8; ++i) af[i] = a_lds[(ty * 8 + i) * 33 + kc];
            #pragma unroll
            for (int j = 0; j < 8; ++j) bf[j] = b_lds[kc * 129 + tx + 16 * j];
            #pragma unroll
            for (int i = 0; i < 8; ++i)
                #pragma unroll
                for (int j = 0; j < 8; ++j)
                    acc[i][j] += af[i] * bf[j];
        }
        __syncthreads();
    }
    #pragma unroll
    for (int i = 0; i < 8; ++i) {
        int o = o0 + ty * 8 + i;
        float bv = bias ? bias[o] : 0.f;
        #pragma unroll
        for (int j = 0; j < 8; ++j)
            Cg[o * P_TOT + p0 + tx + 16 * j] = acc[i][j] + bv;
    }
}

// ------- l2-normalize q,k in place; additionally emit qT bf16 [h][p][32] -----
__global__ __launch_bounds__(256) void k_norm(float* __restrict__ qk,
                                              u16* __restrict__ qT) {
    int p = blockIdx.x * 256 + threadIdx.x;
    for (int grp = 0; grp < 16; ++grp) {   // 8 q-heads then 8 k-heads
        float v[32]; float ssq = 0.f;
        #pragma unroll
        for (int c = 0; c < 32; ++c) {
            v[c] = qk[(grp * 32 + c) * P_TOT + p];
            ssq += v[c] * v[c];
        }
        float n  = sqrtf(ssq);
        float sc = 1.f / fmaxf(n, 1e-12f);
        #pragma unroll
        for (int c = 0; c < 32; ++c) {
            v[c] *= sc;
            qk[(grp * 32 + c) * P_TOT + p] = v[c];
        }
        if (grp < 8) {
            u32* qrow = (u32*)(qT + ((size_t)grp * P_TOT + p) * 32);
            #pragma unroll
            for (int i = 0; i < 16; ++i)
                qrow[i] = bf16pair(v[2 * i], v[2 * i + 1]);
        }
    }
}

// ---------------- probes: per (row o, d): total, per-h sums, per-w sums ------
__global__ __launch_bounds__(256) void k_probe(const float* __restrict__ qk,
                                               float* __restrict__ pd,
                                               float* __restrict__ pdh,
                                               float* __restrict__ pdw) {
    int o = blockIdx.x;   // 0..511
    int d = blockIdx.y;   // 0..15
    int t = threadIdx.x;
    __shared__ float ph2[64 * 65];
    __shared__ float pwl[256];
    for (int i = t; i < 64 * 65; i += 256) ph2[i] = 0.f;
    __syncthreads();
    const float* src = qk + o * P_TOT + d * 4096;
    int col = t & 63;
    int tg  = t >> 6;
    float wsum = 0.f;
    #pragma unroll
    for (int r = 0; r < 16; ++r) {
        int i = t + 256 * r;
        float val = fabsf(src[i]);
        wsum += val;
        int h = 4 * r + tg;
        ph2[h * 65 + col] += val;
    }
    pwl[t] = wsum;
    __syncthreads();
    if (t < 64) {
        float s = 0.f;
        for (int cc = 0; cc < 64; ++cc) s += ph2[t * 65 + cc];
        pdh[(o * 16 + d) * 64 + t] = s;
        ph2[t * 65 + 64] = s;
    } else if (t < 128) {
        int w = t - 64;
        float s = 0.f;
        for (int g2 = 0; g2 < 4; ++g2) s += pwl[g2 * 64 + w];
        pdw[(o * 16 + d) * 64 + w] = s;
    }
    __syncthreads();
    if (t == 0) {
        float s = 0.f;
        for (int h = 0; h < 64; ++h) s += ph2[h * 65 + 64];
        pd[o * 16 + d] = s;
    }
}

// ---------------- top-k kernels ----------------
__global__ __launch_bounds__(64) void k_topk_d(const float* __restrict__ pd,
                                               int* __restrict__ idx_d) {
    int h = blockIdx.x, t = threadIdx.x;
    __shared__ float sc[16];
    if (t < 16) {
        float s = 0.f;
        for (int c = 0; c < 32; ++c)
            s += pd[(h * 32 + c) * 16 + t] * pd[(256 + h * 32 + c) * 16 + t];
        sc[t] = s;
    }
    __syncthreads();
    if (t == 0) {
        bool used[16] = {};
        for (int r = 0; r < KD; ++r) {
            int best = 0; float bv = -1e30f;
            for (int i = 0; i < 16; ++i)
                if (!used[i] && sc[i] > bv) { bv = sc[i]; best = i; }
            used[best] = true;
            idx_d[h * KD + r] = best;
        }
    }
}

__global__ __launch_bounds__(64) void k_topk_h(const float* __restrict__ pdh,
                                               const int* __restrict__ idx_d,
                                               int* __restrict__ idx_h) {
    int h = blockIdx.x, t = threadIdx.x;
    __shared__ float sc[64];
    int ds[KD];
    for (int i = 0; i < KD; ++i) ds[i] = idx_d[h * KD + i];
    float s = 0.f;
    for (int c = 0; c < 32; ++c) {
        int oq = h * 32 + c, ok = 256 + h * 32 + c;
        float qp = 0.f;
        for (int d = 0; d < 16; ++d) qp += pdh[(oq * 16 + d) * 64 + t];
        float kp = 0.f;
        for (int i = 0; i < KD; ++i) kp += pdh[(ok * 16 + ds[i]) * 64 + t];
        s += qp * kp;
    }
    sc[t] = s;
    __syncthreads();
    if (t == 0) {
        bool used[64] = {};
        for (int r = 0; r < KH; ++r) {
            int best = 0; float bv = -1e30f;
            for (int i = 0; i < 64; ++i)
                if (!used[i] && sc[i] > bv) { bv = sc[i]; best = i; }
            used[best] = true;
            idx_h[h * KH + r] = best;
        }
    }
}

__global__ __launch_bounds__(64) void k_probe_w(const float* __restrict__ qk,
                                                const int* __restrict__ idx_d,
                                                const int* __restrict__ idx_h,
                                                float* __restrict__ kpw) {
    int o2 = blockIdx.x;
    int w  = threadIdx.x;
    int h  = o2 >> 5;
    const float* src = qk + (256 + o2) * P_TOT;
    float s = 0.f;
    for (int i = 0; i < KD; ++i) {
        int pb = idx_d[h * KD + i] * 4096;
        for (int j = 0; j < KH; ++j)
            s += fabsf(src[pb + idx_h[h * KH + j] * 64 + w]);
    }
    kpw[o2 * 64 + w] = s;
}

__global__ __launch_bounds__(64) void k_topk_w(const float* __restrict__ pdw,
                                               const float* __restrict__ kpw,
                                               int* __restrict__ idx_w) {
    int h = blockIdx.x, t = threadIdx.x;
    __shared__ float sc[64];
    float s = 0.f;
    for (int c = 0; c < 32; ++c) {
        int oq = h * 32 + c;
        float qp = 0.f;
        for (int d = 0; d < 16; ++d) qp += pdw[(oq * 16 + d) * 64 + t];
        s += qp * kpw[(h * 32 + c) * 64 + t];
    }
    sc[t] = s;
    __syncthreads();
    if (t == 0) {
        bool used[64] = {};
        for (int r = 0; r < KW; ++r) {
            int best = 0; float bv = -1e30f;
            for (int i = 0; i < 64; ++i)
                if (!used[i] && sc[i] > bv) { bv = sc[i]; best = i; }
            used[best] = true;
            idx_w[h * KW + r] = best;
        }
    }
}

// ------- gather pruned k (bf16 [h][j][32]) + recompute v (bf16 [h][c][256]) ---
__global__ __launch_bounds__(64) void k_gather(const float* __restrict__ qk,
                                               const u16* __restrict__ xnT_hi,
                                               const u16* __restrict__ xnT_lo,
                                               const float* __restrict__ wqkv,
                                               const int* __restrict__ idx_d,
                                               const int* __restrict__ idx_h,
                                               const int* __restrict__ idx_w,
                                               u16* __restrict__ kb,
                                               u16* __restrict__ vT) {
    int h  = blockIdx.x;          // 0..7
    int jb = blockIdx.y;          // 0..127
    int t  = threadIdx.x;         // 0..63
    int j  = jb * 2 + (t >> 5);
    int c  = t & 31;
    int di = j >> 6, hi = (j >> 3) & 7, wi = j & 7;
    int p  = idx_d[h * KD + di] * 4096 + idx_h[h * KH + hi] * 64 + idx_w[h * KW + wi];
    kb[(h * NJ + j) * 32 + c] = bf16r(qk[(256 + h * 32 + c) * P_TOT + p]);
    const float* wr = wqkv + (512 + h * 32 + c) * CH;
    const u16* xh = xnT_hi + (size_t)p * 128;
    const u16* xl = xnT_lo + (size_t)p * 128;
    float acc = 0.f;
    for (int cc = 0; cc < CH; ++cc)
        acc += wr[cc] * (bf16f(xh[cc]) + bf16f(xl[cc]));
    vT[((size_t)h * 32 + c) * NJ + j] = bf16r(acc);
}

// ------- MFMA flash attention: one wave = 16 queries ------------------------
// Output written in the reference's scrambled reshape layout (see R2 note).
__global__ __launch_bounds__(256) void k_attn(const u16* __restrict__ qT,
                                              const u16* __restrict__ kb,
                                              const u16* __restrict__ vT,
                                              float* __restrict__ attn) {
    __shared__ u16 sP[4 * 16 * 264];
    int h    = blockIdx.x >> 10;
    int pb   = blockIdx.x & 1023;
    int wave = threadIdx.x >> 6;
    int lane = threadIdx.x & 63;
    int m    = lane & 15;
    int quad = lane >> 4;
    u16* sPw = sP + wave * (16 * 264);

    int q0 = pb * 64 + wave * 16;
    int p  = q0 + m;

    frag8 bq = *(const frag8*)(qT + ((size_t)h * P_TOT + p) * 32 + quad * 8);
    const u16* kbase = kb + (size_t)h * NJ * 32;

    f32x4 zero = {0.f, 0.f, 0.f, 0.f};
    float den = 0.f;
    #pragma unroll
    for (int t = 0; t < 16; ++t) {
        frag8 ak = *(const frag8*)(kbase + (t * 16 + m) * 32 + quad * 8);
        f32x4 st = __builtin_amdgcn_mfma_f32_16x16x32_bf16(ak, bq, zero, 0, 0, 0);
        float e0 = __expf(st[0]);
        float e1 = __expf(st[1]);
        float e2 = __expf(st[2]);
        float e3 = __expf(st[3]);
        den += (e0 + e1) + (e2 + e3);
        u32* dst = (u32*)(sPw + m * 264 + t * 16 + quad * 4);
        dst[0] = bf16pair(e0, e1);
        dst[1] = bf16pair(e2, e3);
    }
    den += __shfl_xor(den, 16, 64);
    den += __shfl_xor(den, 32, 64);
    __syncthreads();

    const u16* vbase = vT + (size_t)h * 32 * NJ;
    f32x4 acc0 = {0.f, 0.f, 0.f, 0.f}, acc1 = {0.f, 0.f, 0.f, 0.f};
    #pragma unroll
    for (int jc = 0; jc < 8; ++jc) {
        frag8 bp  = *(const frag8*)(sPw + m * 264 + jc * 32 + quad * 8);
        frag8 av0 = *(const frag8*)(vbase + (size_t)m * NJ + jc * 32 + quad * 8);
        frag8 av1 = *(const frag8*)(vbase + (size_t)(16 + m) * NJ + jc * 32 + quad * 8);
        acc0 = __builtin_amdgcn_mfma_f32_16x16x32_bf16(av0, bp, acc0, 0, 0, 0);
        acc1 = __builtin_amdgcn_mfma_f32_16x16x32_bf16(av1, bp, acc1, 0, 0, 0);
    }
    float inv = 1.f / den;
    size_t base = ((size_t)(h * 32 + (p >> 11))) * P_TOT + (size_t)(p & 2047) * 32;
    float4 o0, o1;
    o0.x = acc0[0] * inv; o0.y = acc0[1] * inv; o0.z = acc0[2] * inv; o0.w = acc0[3] * inv;
    o1.x = acc1[0] * inv; o1.y = acc1[1] * inv; o1.z = acc1[2] * inv; o1.w = acc1[3] * inv;
    *(float4*)(attn + base + quad * 4)      = o0;
    *(float4*)(attn + base + 16 + quad * 4) = o1;
}

extern "C" void kernel_launch(void* const* d_in, const int* in_sizes, int n_in,
                              void* d_out, int out_size, void* d_ws, size_t ws_size,
                              hipStream_t stream) {
    const float* x    = (const float*)d_in[0];
    const float* g    = (const float*)d_in[1];
    const float* b    = (const float*)d_in[2];
    const float* wqkv = (const float*)d_in[3];
    const float* wout = (const float*)d_in[4];
    const float* bout = (const float*)d_in[5];
    float* out = (float*)d_out;
    float* ws  = (float*)d_ws;

    // ws layout (floats unless noted):
    u16*   xnT_hi = (u16*)ws;               // 128*65536 u16
    u16*   xnT_lo = xnT_hi + 8388608;       // 128*65536 u16 (both = 8,388,608 floats)
    float* qk   = ws + 8388608;             // 512*65536 (q rows 0..255, k rows 256..511)
    float* attn = qk + 256 * P_TOT;         // overlays k rows after gather
    float* aux  = ws + 41943040;
    float* pd    = aux;                     // 8192
    float* pdh   = pd + 8192;               // 524288
    float* pdw   = pdh + 524288;            // 524288
    float* kpw   = pdw + 524288;            // 16384
    int*   idx_d = (int*)(kpw + 16384);     // 32
    int*   idx_h = idx_d + 32;              // 64
    int*   idx_w = idx_h + 64;              // 64
    u16*   kb    = (u16*)(idx_w + 64);      // 8*256*32 bf16
    u16*   vT    = kb + 8 * NJ * 32;        // 8*32*256 bf16
    u16*   qT    = vT + 8 * 32 * NJ;        // 8*65536*32 bf16 (33.5 MB)
    u16*   w_hi  = qT + (size_t)8 * P_TOT * 32;  // 512*128 bf16
    u16*   w_lo  = w_hi + 512 * 128;             // 512*128 bf16

    k_ln<<<256, 256, 0, stream>>>(x, g, b, xnT_hi, xnT_lo);
    k_wsplit<<<256, 256, 0, stream>>>(wqkv, w_hi, w_lo);
    k_gemm_qkv<<<dim3(512, 4), 256, 0, stream>>>(xnT_hi, xnT_lo, w_hi, w_lo, qk);
    k_norm<<<256, 256, 0, stream>>>(qk, qT);
    k_probe<<<dim3(512, 16), 256, 0, stream>>>(qk, pd, pdh, pdw);
    k_topk_d<<<8, 64, 0, stream>>>(pd, idx_d);
    k_topk_h<<<8, 64, 0, stream>>>(pdh, idx_d, idx_h);
    k_probe_w<<<256, 64, 0, stream>>>(qk, idx_d, idx_h, kpw);
    k_topk_w<<<8, 64, 0, stream>>>(pdw, kpw, idx_w);
    k_gather<<<dim3(8, 128), 64, 0, stream>>>(qk, xnT_hi, xnT_lo, wqkv,
                                              idx_d, idx_h, idx_w, kb, vT);
    k_attn<<<8192, 256, 0, stream>>>(qT, kb, vT, attn);
    k_gemm<<<dim3(512, 1), 256, 0, stream>>>(wout, 256, 256, attn, out, bout);
}

// Round 6
// 443.359 us; speedup vs baseline: 1.7607x; 1.4450x over previous
//
#include <hip/hip_runtime.h>
#include <math.h>

#define P_TOT 65536   // 16*64*64 spatial positions
#define CH    128     // channels
#define NHEAD 8
#define KD    4
#define KH    8
#define KW    8
#define NJ    256     // KD*KH*KW keys per head

typedef unsigned short u16;
typedef unsigned int   u32;
typedef __attribute__((ext_vector_type(8))) short frag8;   // bf16x8 (4 VGPRs)
typedef __attribute__((ext_vector_type(4))) float f32x4;   // MFMA C/D

__device__ inline u16 bf16r(float a) {                     // RTNE round
    u32 ua = __float_as_uint(a);
    return (u16)((ua + 0x7fff + ((ua >> 16) & 1)) >> 16);
}
__device__ inline float bf16f(u16 h) {
    return __uint_as_float(((u32)h) << 16);
}
__device__ inline u32 packhl(float v) {                    // hi | lo<<16
    u16 hh = bf16r(v);
    u16 ll = bf16r(v - bf16f(hh));
    return (u32)hh | ((u32)ll << 16);
}

// ---- LayerNorm, 64p x 128c tile; emits packed bf16 hi|lo plane xnT_pk[p][c] --
// Coalesced loads -> LDS [c][p]; per-p stats; in-LDS transpose into tr[p][c]
// (u32, row stride 131: odd => transpose-write banks (3*lane+c)%32 conflict-
// free); coalesced 16B-chunk stores covering all 128 channels.
__global__ __launch_bounds__(256) void k_ln(const float* __restrict__ x,
                                            const float* __restrict__ g,
                                            const float* __restrict__ b,
                                            u32* __restrict__ xnT_pk) {
    __shared__ u32 buf[64 * 131];         // 33.5 KB: xt (32 KB floats) then tr
    __shared__ float red[8 * 64];
    __shared__ float stat[2 * 64];
    float* xt = (float*)buf;              // [c][pp] 128x64
    int t  = threadIdx.x;
    int p0 = blockIdx.x * 64;
    #pragma unroll
    for (int r = 0; r < 8; ++r) {         // load tile: 2048 float4 chunks
        int id = t + 256 * r;
        int c = id >> 4, q4 = id & 15;
        *(float4*)(xt + c * 64 + q4 * 4) =
            *(const float4*)(x + (size_t)c * P_TOT + p0 + q4 * 4);
    }
    __syncthreads();
    int pp = t & 63, part = t >> 6;
    float sum = 0.f, ssq = 0.f;
    for (int ci = 0; ci < 32; ++ci) {
        float v = xt[(part * 32 + ci) * 64 + pp];
        sum += v; ssq += v * v;
    }
    red[part * 64 + pp] = sum;
    red[256 + part * 64 + pp] = ssq;
    __syncthreads();
    if (t < 64) {
        float s = red[t] + red[64 + t] + red[128 + t] + red[192 + t];
        float q = red[256 + t] + red[320 + t] + red[384 + t] + red[448 + t];
        float mean = s * (1.f / CH);
        float var  = q * (1.f / CH) - mean * mean;
        stat[t] = mean;
        stat[64 + t] = 1.f / sqrtf(var + 1e-5f);
    }
    __syncthreads();
    float mean = stat[pp], inv = stat[64 + pp];
    u32 pk[32];
    for (int ci = 0; ci < 32; ++ci) {
        int c = part * 32 + ci;
        float v  = xt[c * 64 + pp];
        float xn = (v - mean) * inv * g[c] + b[c];
        pk[ci] = packhl(xn);
    }
    __syncthreads();                      // all xt reads done; reuse buf as tr
    u32* tr = buf;                        // [pp][c] stride 131
    for (int ci = 0; ci < 32; ++ci)
        tr[pp * 131 + part * 32 + ci] = pk[ci];
    __syncthreads();
    #pragma unroll
    for (int r = 0; r < 8; ++r) {         // store: 2048 chunks of 16 B
        int id = t + 256 * r;
        int pr = id >> 5, ch = id & 31;
        const u32* srcp = tr + pr * 131 + ch * 4;
        uint4 v4;
        v4.x = srcp[0]; v4.y = srcp[1]; v4.z = srcp[2]; v4.w = srcp[3];
        *(uint4*)(xnT_pk + (size_t)(p0 + pr) * 128 + ch * 4) = v4;
    }
}

// ---- split qkv (first 512 rows) and wout into bf16 hi/lo planes ------------
__global__ __launch_bounds__(256) void k_wsplit(const float* __restrict__ wqkv,
                                                const float* __restrict__ wout,
                                                u16* __restrict__ w_hi,
                                                u16* __restrict__ w_lo,
                                                u16* __restrict__ w2_hi,
                                                u16* __restrict__ w2_lo) {
    int id = blockIdx.x * 256 + threadIdx.x;   // 0..98303
    if (id < 65536) {
        float v = wqkv[id];
        u16 hh = bf16r(v);
        w_hi[id] = hh; w_lo[id] = bf16r(v - bf16f(hh));
    } else {
        int j = id - 65536;                    // 128*256 wout
        float v = wout[j];
        u16 hh = bf16r(v);
        w2_hi[j] = hh; w2_lo[j] = bf16r(v - bf16f(hh));
    }
}

// ---- MFMA qkv GEMM: qk[o][p] = sum_k w[o][k]*xn[k][p], bf16x3 in one sweep --
// A = xnT_pk rows (m=p, k contiguous, packed hi|lo), B = w hi/lo planes.
// LDS 128x64 u16 x4 planes, XOR-16B granule swizzle. D: col=o, row=p.
__global__ __launch_bounds__(256) void k_gemm_qkv(const u32* __restrict__ xnT_pk,
                                                  const u16* __restrict__ w_hi,
                                                  const u16* __restrict__ w_lo,
                                                  float* __restrict__ qk) {
    __shared__ u16 a_hi[128 * 64], a_lo[128 * 64];
    __shared__ u16 b_hi[128 * 64], b_lo[128 * 64];
    int t    = threadIdx.x;
    int lane = t & 63, wave = t >> 6;
    int wp = wave & 1, wo = wave >> 1;
    int m = lane & 15, quad = lane >> 4;
    int p0 = blockIdx.x * 128;
    int o0 = blockIdx.y * 128;
    f32x4 acc[4][4] = {};
    for (int k0 = 0; k0 < 128; k0 += 64) {
        __syncthreads();
        #pragma unroll
        for (int r = 0; r < 4; ++r) {      // 1024 granules: row=id>>3, g=id&7
            int id  = t + 256 * r;
            int row = id >> 3, gg = id & 7;
            int go  = (gg ^ (row & 7)) * 8;
            const u32* src = xnT_pk + (size_t)(p0 + row) * 128 + k0 + gg * 8;
            u32 pkk[8];
            *(uint4*)pkk       = *(const uint4*)src;
            *(uint4*)(pkk + 4) = *(const uint4*)(src + 4);
            u32 hi4[4], lo4[4];
            #pragma unroll
            for (int e = 0; e < 4; ++e) {
                hi4[e] = __builtin_amdgcn_perm(pkk[2*e+1], pkk[2*e], 0x05040100);
                lo4[e] = __builtin_amdgcn_perm(pkk[2*e+1], pkk[2*e], 0x07060302);
            }
            *(uint4*)(a_hi + row * 64 + go) = *(uint4*)hi4;
            *(uint4*)(a_lo + row * 64 + go) = *(uint4*)lo4;
            *(uint4*)(b_hi + row * 64 + go) =
                *(const uint4*)(w_hi + (size_t)(o0 + row) * 128 + k0 + gg * 8);
            *(uint4*)(b_lo + row * 64 + go) =
                *(const uint4*)(w_lo + (size_t)(o0 + row) * 128 + k0 + gg * 8);
        }
        __syncthreads();
        #pragma unroll
        for (int ks = 0; ks < 2; ++ks) {
            frag8 ah[4], al[4], bh[4], bl[4];
            #pragma unroll
            for (int i = 0; i < 4; ++i) {
                int row = wp * 64 + i * 16 + m;
                int gg  = (ks * 4 + quad) ^ (row & 7);
                ah[i] = *(const frag8*)(a_hi + row * 64 + gg * 8);
                al[i] = *(const frag8*)(a_lo + row * 64 + gg * 8);
            }
            #pragma unroll
            for (int j = 0; j < 4; ++j) {
                int row = wo * 64 + j * 16 + m;
                int gg  = (ks * 4 + quad) ^ (row & 7);
                bh[j] = *(const frag8*)(b_hi + row * 64 + gg * 8);
                bl[j] = *(const frag8*)(b_lo + row * 64 + gg * 8);
            }
            #pragma unroll
            for (int i = 0; i < 4; ++i)
                #pragma unroll
                for (int j = 0; j < 4; ++j) {
                    acc[i][j] = __builtin_amdgcn_mfma_f32_16x16x32_bf16(ah[i], bh[j], acc[i][j], 0, 0, 0);
                    acc[i][j] = __builtin_amdgcn_mfma_f32_16x16x32_bf16(ah[i], bl[j], acc[i][j], 0, 0, 0);
                    acc[i][j] = __builtin_amdgcn_mfma_f32_16x16x32_bf16(al[i], bh[j], acc[i][j], 0, 0, 0);
                }
        }
    }
    #pragma unroll
    for (int i = 0; i < 4; ++i) {
        int p = p0 + wp * 64 + i * 16 + quad * 4;
        #pragma unroll
        for (int j = 0; j < 4; ++j) {
            int o = o0 + wo * 64 + j * 16 + m;
            float4 v;
            v.x = acc[i][j][0]; v.y = acc[i][j][1];
            v.z = acc[i][j][2]; v.w = acc[i][j][3];
            *(float4*)(qk + (size_t)o * P_TOT + p) = v;
        }
    }
}

// ------- l2-normalize q,k in place; additionally emit qT bf16 [h][p][32] -----
__global__ __launch_bounds__(256) void k_norm(float* __restrict__ qk,
                                              u16* __restrict__ qT) {
    int p = blockIdx.x * 256 + threadIdx.x;
    for (int grp = 0; grp < 16; ++grp) {
        float v[32]; float ssq = 0.f;
        #pragma unroll
        for (int c = 0; c < 32; ++c) {
            v[c] = qk[(grp * 32 + c) * P_TOT + p];
            ssq += v[c] * v[c];
        }
        float n  = sqrtf(ssq);
        float sc = 1.f / fmaxf(n, 1e-12f);
        #pragma unroll
        for (int c = 0; c < 32; ++c) {
            v[c] *= sc;
            qk[(grp * 32 + c) * P_TOT + p] = v[c];
        }
        if (grp < 8) {
            u16 row[32];
            #pragma unroll
            for (int c = 0; c < 32; ++c) row[c] = bf16r(v[c]);
            uint4* q4 = (uint4*)(qT + ((size_t)grp * P_TOT + p) * 32);
            q4[0] = *(uint4*)row; q4[1] = *(uint4*)(row + 8);
            q4[2] = *(uint4*)(row + 16); q4[3] = *(uint4*)(row + 24);
        }
    }
}

// ---------------- probes: per (row o, d): total, per-h sums, per-w sums ------
__global__ __launch_bounds__(256) void k_probe(const float* __restrict__ qk,
                                               float* __restrict__ pd,
                                               float* __restrict__ pdh,
                                               float* __restrict__ pdw) {
    int o = blockIdx.x;   // 0..511
    int d = blockIdx.y;   // 0..15
    int t = threadIdx.x;
    __shared__ float ph2[64 * 65];
    __shared__ float pwl[256];
    for (int i = t; i < 64 * 65; i += 256) ph2[i] = 0.f;
    __syncthreads();
    const float* src = qk + o * P_TOT + d * 4096;
    int col = t & 63;
    int tg  = t >> 6;
    float wsum = 0.f;
    #pragma unroll
    for (int r = 0; r < 16; ++r) {
        int i = t + 256 * r;
        float val = fabsf(src[i]);
        wsum += val;
        int h = 4 * r + tg;
        ph2[h * 65 + col] += val;
    }
    pwl[t] = wsum;
    __syncthreads();
    if (t < 64) {
        float s = 0.f;
        for (int cc = 0; cc < 64; ++cc) s += ph2[t * 65 + cc];
        pdh[(o * 16 + d) * 64 + t] = s;
        ph2[t * 65 + 64] = s;
    } else if (t < 128) {
        int w = t - 64;
        float s = 0.f;
        for (int g2 = 0; g2 < 4; ++g2) s += pwl[g2 * 64 + w];
        pdw[(o * 16 + d) * 64 + w] = s;
    }
    __syncthreads();
    if (t == 0) {
        float s = 0.f;
        for (int h = 0; h < 64; ++h) s += ph2[h * 65 + 64];
        pd[o * 16 + d] = s;
    }
}

// ---- reduce probes over d: qph[o][t]=sum_d pdh, qpw[o][t]=sum_d pdw --------
__global__ __launch_bounds__(64) void k_psum(const float* __restrict__ pdh,
                                             const float* __restrict__ pdw,
                                             float* __restrict__ qph,
                                             float* __restrict__ qpw) {
    int o = blockIdx.x, t = threadIdx.x;
    float sh = 0.f, sw = 0.f;
    #pragma unroll
    for (int d = 0; d < 16; ++d) {
        sh += pdh[(o * 16 + d) * 64 + t];
        sw += pdw[(o * 16 + d) * 64 + t];
    }
    qph[o * 64 + t] = sh;
    qpw[o * 64 + t] = sw;
}

// ---------------- top-k kernels ----------------
__global__ __launch_bounds__(64) void k_topk_d(const float* __restrict__ pd,
                                               int* __restrict__ idx_d) {
    int h = blockIdx.x, t = threadIdx.x;
    __shared__ float sc[16];
    if (t < 16) {
        float s = 0.f;
        for (int c = 0; c < 32; ++c)
            s += pd[(h * 32 + c) * 16 + t] * pd[(256 + h * 32 + c) * 16 + t];
        sc[t] = s;
    }
    __syncthreads();
    if (t == 0) {
        bool used[16] = {};
        for (int r = 0; r < KD; ++r) {
            int best = 0; float bv = -1e30f;
            for (int i = 0; i < 16; ++i)
                if (!used[i] && sc[i] > bv) { bv = sc[i]; best = i; }
            used[best] = true;
            idx_d[h * KD + r] = best;
        }
    }
}

__global__ __launch_bounds__(256) void k_topk_h(const float* __restrict__ qph,
                                                const float* __restrict__ pdh,
                                                const int* __restrict__ idx_d,
                                                int* __restrict__ idx_h) {
    int h = blockIdx.x, t = threadIdx.x;
    int tq = t & 63, cg = t >> 6;
    __shared__ float sc2[4][64];
    __shared__ float sc[64];
    int ds[KD];
    #pragma unroll
    for (int i = 0; i < KD; ++i) ds[i] = idx_d[h * KD + i];
    float partial = 0.f;
    for (int ci = 0; ci < 8; ++ci) {
        int c  = cg * 8 + ci;
        int oq = h * 32 + c, ok = 256 + h * 32 + c;
        float qp = qph[oq * 64 + tq];
        float kp = 0.f;
        #pragma unroll
        for (int i = 0; i < KD; ++i) kp += pdh[(ok * 16 + ds[i]) * 64 + tq];
        partial += qp * kp;
    }
    sc2[cg][tq] = partial;
    __syncthreads();
    if (t < 64) sc[t] = sc2[0][t] + sc2[1][t] + sc2[2][t] + sc2[3][t];
    __syncthreads();
    if (t == 0) {
        bool used[64] = {};
        for (int r = 0; r < KH; ++r) {
            int best = 0; float bv = -1e30f;
            for (int i = 0; i < 64; ++i)
                if (!used[i] && sc[i] > bv) { bv = sc[i]; best = i; }
            used[best] = true;
            idx_h[h * KH + r] = best;
        }
    }
}

__global__ __launch_bounds__(64) void k_probe_w(const float* __restrict__ qk,
                                                const int* __restrict__ idx_d,
                                                const int* __restrict__ idx_h,
                                                float* __restrict__ kpw) {
    int o2 = blockIdx.x;
    int w  = threadIdx.x;
    int h  = o2 >> 5;
    const float* src = qk + (256 + o2) * P_TOT;
    float s = 0.f;
    for (int i = 0; i < KD; ++i) {
        int pb = idx_d[h * KD + i] * 4096;
        for (int j = 0; j < KH; ++j)
            s += fabsf(src[pb + idx_h[h * KH + j] * 64 + w]);
    }
    kpw[o2 * 64 + w] = s;
}

__global__ __launch_bounds__(256) void k_topk_w(const float* __restrict__ qpw,
                                                const float* __restrict__ kpw,
                                                int* __restrict__ idx_w) {
    int h = blockIdx.x, t = threadIdx.x;
    int tq = t & 63, cg = t >> 6;
    __shared__ float sc2[4][64];
    __shared__ float sc[64];
    float partial = 0.f;
    for (int ci = 0; ci < 8; ++ci) {
        int c  = cg * 8 + ci;
        int oq = h * 32 + c;
        partial += qpw[oq * 64 + tq] * kpw[(h * 32 + c) * 64 + tq];
    }
    sc2[cg][tq] = partial;
    __syncthreads();
    if (t < 64) sc[t] = sc2[0][t] + sc2[1][t] + sc2[2][t] + sc2[3][t];
    __syncthreads();
    if (t == 0) {
        bool used[64] = {};
        for (int r = 0; r < KW; ++r) {
            int best = 0; float bv = -1e30f;
            for (int i = 0; i < 64; ++i)
                if (!used[i] && sc[i] > bv) { bv = sc[i]; best = i; }
            used[best] = true;
            idx_w[h * KW + r] = best;
        }
    }
}

// ------- gather pruned k (bf16 [h][j][32]) + recompute v (bf16 [h][c][256]) ---
__global__ __launch_bounds__(64) void k_gather(const float* __restrict__ qk,
                                               const u32* __restrict__ xnT_pk,
                                               const float* __restrict__ wqkv,
                                               const int* __restrict__ idx_d,
                                               const int* __restrict__ idx_h,
                                               const int* __restrict__ idx_w,
                                               u16* __restrict__ kb,
                                               u16* __restrict__ vT) {
    int h  = blockIdx.x;          // 0..7
    int jb = blockIdx.y;          // 0..127
    int t  = threadIdx.x;         // 0..63
    int j  = jb * 2 + (t >> 5);
    int c  = t & 31;
    int di = j >> 6, hi = (j >> 3) & 7, wi = j & 7;
    int p  = idx_d[h * KD + di] * 4096 + idx_h[h * KH + hi] * 64 + idx_w[h * KW + wi];
    kb[(h * NJ + j) * 32 + c] = bf16r(qk[(256 + h * 32 + c) * P_TOT + p]);
    const float* wr = wqkv + (512 + h * 32 + c) * CH;
    const u32* xp = xnT_pk + (size_t)p * 128;
    float acc = 0.f;
    for (int cc = 0; cc < CH; ++cc) {
        u32 pk = xp[cc];
        float v = __uint_as_float(pk << 16) + __uint_as_float(pk & 0xffff0000u);
        acc += wr[cc] * v;
    }
    vT[((size_t)h * 32 + c) * NJ + j] = bf16r(acc);
}

// ------- MFMA flash attention: one wave = 16 queries ------------------------
// Output written packed (bf16 hi|lo u32) in the scrambled reshape layout.
__global__ __launch_bounds__(256) void k_attn(const u16* __restrict__ qT,
                                              const u16* __restrict__ kb,
                                              const u16* __restrict__ vT,
                                              u32* __restrict__ attn_pk) {
    __shared__ u16 sP[4 * 16 * 264];
    int h    = blockIdx.x >> 10;
    int pb   = blockIdx.x & 1023;
    int wave = threadIdx.x >> 6;
    int lane = threadIdx.x & 63;
    int m    = lane & 15;
    int quad = lane >> 4;
    u16* sPw = sP + wave * (16 * 264);

    int q0 = pb * 64 + wave * 16;
    int p  = q0 + m;

    frag8 bq = *(const frag8*)(qT + ((size_t)h * P_TOT + p) * 32 + quad * 8);
    const u16* kbase = kb + (size_t)h * NJ * 32;

    f32x4 zero = {0.f, 0.f, 0.f, 0.f};
    float den = 0.f;
    #pragma unroll
    for (int t = 0; t < 16; ++t) {
        frag8 ak = *(const frag8*)(kbase + (t * 16 + m) * 32 + quad * 8);
        f32x4 st = __builtin_amdgcn_mfma_f32_16x16x32_bf16(ak, bq, zero, 0, 0, 0);
        float e0 = __expf(st[0]);
        float e1 = __expf(st[1]);
        float e2 = __expf(st[2]);
        float e3 = __expf(st[3]);
        den += (e0 + e1) + (e2 + e3);
        u16* dst = sPw + m * 264 + t * 16 + quad * 4;
        dst[0] = bf16r(e0); dst[1] = bf16r(e1);
        dst[2] = bf16r(e2); dst[3] = bf16r(e3);
    }
    den += __shfl_xor(den, 16, 64);
    den += __shfl_xor(den, 32, 64);
    __syncthreads();

    const u16* vbase = vT + (size_t)h * 32 * NJ;
    f32x4 acc0 = {0.f, 0.f, 0.f, 0.f}, acc1 = {0.f, 0.f, 0.f, 0.f};
    #pragma unroll
    for (int jc = 0; jc < 8; ++jc) {
        frag8 bp  = *(const frag8*)(sPw + m * 264 + jc * 32 + quad * 8);
        frag8 av0 = *(const frag8*)(vbase + (size_t)m * NJ + jc * 32 + quad * 8);
        frag8 av1 = *(const frag8*)(vbase + (size_t)(16 + m) * NJ + jc * 32 + quad * 8);
        acc0 = __builtin_amdgcn_mfma_f32_16x16x32_bf16(av0, bp, acc0, 0, 0, 0);
        acc1 = __builtin_amdgcn_mfma_f32_16x16x32_bf16(av1, bp, acc1, 0, 0, 0);
    }
    float inv = 1.f / den;
    size_t base = ((size_t)(h * 32 + (p >> 11))) * P_TOT + (size_t)(p & 2047) * 32;
    uint4 o0, o1;
    o0.x = packhl(acc0[0] * inv); o0.y = packhl(acc0[1] * inv);
    o0.z = packhl(acc0[2] * inv); o0.w = packhl(acc0[3] * inv);
    o1.x = packhl(acc1[0] * inv); o1.y = packhl(acc1[1] * inv);
    o1.z = packhl(acc1[2] * inv); o1.w = packhl(acc1[3] * inv);
    *(uint4*)(attn_pk + base + quad * 4)      = o0;
    *(uint4*)(attn_pk + base + 16 + quad * 4) = o1;
}

// ---- MFMA out-proj: out[o][q] = sum_k wout[o][k]*attn[k][q] + bias ---------
// attn_pk is k-major; transpose tiles into LDS (XOR swizzle) during staging.
__global__ __launch_bounds__(256) void k_gemm_out(const u32* __restrict__ attn_pk,
                                                  const u16* __restrict__ w2_hi,
                                                  const u16* __restrict__ w2_lo,
                                                  const float* __restrict__ bout,
                                                  float* __restrict__ out) {
    __shared__ u16 a_hi[128 * 64], a_lo[128 * 64];   // [q'][k'] swizzled
    __shared__ u16 b_hi[128 * 64], b_lo[128 * 64];   // [o][k'] swizzled
    int t    = threadIdx.x;
    int lane = t & 63, wave = t >> 6;
    int wq = wave & 1, wo = wave >> 1;
    int m = lane & 15, quad = lane >> 4;
    int q0 = blockIdx.x * 128;
    f32x4 acc[4][4] = {};
    for (int k0 = 0; k0 < 256; k0 += 64) {
        __syncthreads();
        #pragma unroll
        for (int r = 0; r < 4; ++r) {      // A: transpose attn[k][q] -> [q][k]
            int id = t + 256 * r;          // qq = id&127 (lane-consecutive), g = id>>7
            int qq = id & 127, gsel = id >> 7;
            u32 pkk[8];
            #pragma unroll
            for (int e = 0; e < 8; ++e)
                pkk[e] = attn_pk[(size_t)(k0 + gsel * 8 + e) * P_TOT + q0 + qq];
            u32 hi4[4], lo4[4];
            #pragma unroll
            for (int e = 0; e < 4; ++e) {
                hi4[e] = __builtin_amdgcn_perm(pkk[2*e+1], pkk[2*e], 0x05040100);
                lo4[e] = __builtin_amdgcn_perm(pkk[2*e+1], pkk[2*e], 0x07060302);
            }
            int go = (gsel ^ (qq & 7)) * 8;
            *(uint4*)(a_hi + qq * 64 + go) = *(uint4*)hi4;
            *(uint4*)(a_lo + qq * 64 + go) = *(uint4*)lo4;
        }
        #pragma unroll
        for (int r = 0; r < 4; ++r) {      // B: wout planes rows 0..127
            int id  = t + 256 * r;
            int row = id >> 3, gg = id & 7;
            int go  = (gg ^ (row & 7)) * 8;
            *(uint4*)(b_hi + row * 64 + go) =
                *(const uint4*)(w2_hi + (size_t)row * 256 + k0 + gg * 8);
            *(uint4*)(b_lo + row * 64 + go) =
                *(const uint4*)(w2_lo + (size_t)row * 256 + k0 + gg * 8);
        }
        __syncthreads();
        #pragma unroll
        for (int ks = 0; ks < 2; ++ks) {
            frag8 ah[4], al[4], bh[4], bl[4];
            #pragma unroll
            for (int i = 0; i < 4; ++i) {
                int row = wq * 64 + i * 16 + m;
                int gg  = (ks * 4 + quad) ^ (row & 7);
                ah[i] = *(const frag8*)(a_hi + row * 64 + gg * 8);
                al[i] = *(const frag8*)(a_lo + row * 64 + gg * 8);
            }
            #pragma unroll
            for (int j = 0; j < 4; ++j) {
                int row = wo * 64 + j * 16 + m;
                int gg  = (ks * 4 + quad) ^ (row & 7);
                bh[j] = *(const frag8*)(b_hi + row * 64 + gg * 8);
                bl[j] = *(const frag8*)(b_lo + row * 64 + gg * 8);
            }
            #pragma unroll
            for (int i = 0; i < 4; ++i)
                #pragma unroll
                for (int j = 0; j < 4; ++j) {
                    acc[i][j] = __builtin_amdgcn_mfma_f32_16x16x32_bf16(ah[i], bh[j], acc[i][j], 0, 0, 0);
                    acc[i][j] = __builtin_amdgcn_mfma_f32_16x16x32_bf16(ah[i], bl[j], acc[i][j], 0, 0, 0);
                    acc[i][j] = __builtin_amdgcn_mfma_f32_16x16x32_bf16(al[i], bh[j], acc[i][j], 0, 0, 0);
                }
        }
    }
    #pragma unroll
    for (int j = 0; j < 4; ++j) {
        int o = wo * 64 + j * 16 + m;
        float bv = bout[o];
        #pragma unroll
        for (int i = 0; i < 4; ++i) {
            int q = q0 + wq * 64 + i * 16 + quad * 4;
            float4 v;
            v.x = acc[i][j][0] + bv; v.y = acc[i][j][1] + bv;
            v.z = acc[i][j][2] + bv; v.w = acc[i][j][3] + bv;
            *(float4*)(out + (size_t)o * P_TOT + q) = v;
        }
    }
}

extern "C" void kernel_launch(void* const* d_in, const int* in_sizes, int n_in,
                              void* d_out, int out_size, void* d_ws, size_t ws_size,
                              hipStream_t stream) {
    const float* x    = (const float*)d_in[0];
    const float* g    = (const float*)d_in[1];
    const float* b    = (const float*)d_in[2];
    const float* wqkv = (const float*)d_in[3];
    const float* wout = (const float*)d_in[4];
    const float* bout = (const float*)d_in[5];
    float* out = (float*)d_out;
    float* ws  = (float*)d_ws;

    // ws layout:
    u32*   xnT_pk = (u32*)ws;               // 128*65536 u32 (packed bf16 hi|lo)
    float* qk   = ws + 8388608;             // 512*65536 fp32 (q rows 0..255, k 256..511)
    u32*   attn_pk = (u32*)(qk + 256 * P_TOT);  // overlays k rows after gather
    float* aux  = ws + 41943040;
    float* pd    = aux;                     // 8192
    float* pdh   = pd + 8192;               // 524288
    float* pdw   = pdh + 524288;            // 524288
    float* kpw   = pdw + 524288;            // 16384
    float* qph   = kpw + 16384;             // 32768
    float* qpw   = qph + 32768;             // 32768
    int*   idx_d = (int*)(qpw + 32768);     // 32
    int*   idx_h = idx_d + 32;              // 64
    int*   idx_w = idx_h + 64;              // 64
    u16*   kb    = (u16*)(idx_w + 64);      // 8*256*32 bf16
    u16*   vT    = kb + 8 * NJ * 32;        // 8*32*256 bf16
    u16*   qT    = vT + 8 * 32 * NJ;        // 8*65536*32 bf16 (33.5 MB)
    u16*   w_hi  = qT + (size_t)8 * P_TOT * 32;  // 512*128
    u16*   w_lo  = w_hi + 512 * 128;             // 512*128
    u16*   w2_hi = w_lo + 512 * 128;             // 128*256
    u16*   w2_lo = w2_hi + 128 * 256;            // 128*256

    k_ln<<<1024, 256, 0, stream>>>(x, g, b, xnT_pk);
    k_wsplit<<<384, 256, 0, stream>>>(wqkv, wout, w_hi, w_lo, w2_hi, w2_lo);
    k_gemm_qkv<<<dim3(512, 4), 256, 0, stream>>>(xnT_pk, w_hi, w_lo, qk);
    k_norm<<<256, 256, 0, stream>>>(qk, qT);
    k_probe<<<dim3(512, 16), 256, 0, stream>>>(qk, pd, pdh, pdw);
    k_psum<<<512, 64, 0, stream>>>(pdh, pdw, qph, qpw);
    k_topk_d<<<8, 64, 0, stream>>>(pd, idx_d);
    k_topk_h<<<8, 256, 0, stream>>>(qph, pdh, idx_d, idx_h);
    k_probe_w<<<256, 64, 0, stream>>>(qk, idx_d, idx_h, kpw);
    k_topk_w<<<8, 256, 0, stream>>>(qpw, kpw, idx_w);
    k_gather<<<dim3(8, 128), 64, 0, stream>>>(qk, xnT_pk, wqkv,
                                              idx_d, idx_h, idx_w, kb, vT);
    k_attn<<<8192, 256, 0, stream>>>(qT, kb, vT, attn_pk);
    k_gemm_out<<<512, 256, 0, stream>>>(attn_pk, w2_hi, w2_lo, bout, out);
}

// Round 7
// 440.064 us; speedup vs baseline: 1.7739x; 1.0075x over previous
//
#include <hip/hip_runtime.h>
#include <math.h>

#define P_TOT 65536   // 16*64*64 spatial positions
#define CH    128     // channels
#define NHEAD 8
#define KD    4
#define KH    8
#define KW    8
#define NJ    256     // KD*KH*KW keys per head

typedef unsigned short u16;
typedef unsigned int   u32;
typedef __attribute__((ext_vector_type(8))) short frag8;   // bf16x8 (4 VGPRs)
typedef __attribute__((ext_vector_type(4))) float f32x4;   // MFMA C/D

__device__ inline u16 bf16r(float a) {                     // RTNE round
    u32 ua = __float_as_uint(a);
    return (u16)((ua + 0x7fff + ((ua >> 16) & 1)) >> 16);
}
__device__ inline float bf16f(u16 h) {
    return __uint_as_float(((u32)h) << 16);
}
__device__ inline u32 packhl(float v) {                    // hi | lo<<16
    u16 hh = bf16r(v);
    u16 ll = bf16r(v - bf16f(hh));
    return (u32)hh | ((u32)ll << 16);
}

// ---- LayerNorm, 64p x 128c tile; emits packed bf16 hi|lo plane xnT_pk[p][c] --
__global__ __launch_bounds__(256) void k_ln(const float* __restrict__ x,
                                            const float* __restrict__ g,
                                            const float* __restrict__ b,
                                            u32* __restrict__ xnT_pk) {
    __shared__ u32 buf[64 * 131];         // 33.5 KB: xt (32 KB floats) then tr
    __shared__ float red[8 * 64];
    __shared__ float stat[2 * 64];
    float* xt = (float*)buf;              // [c][pp] 128x64
    int t  = threadIdx.x;
    int p0 = blockIdx.x * 64;
    #pragma unroll
    for (int r = 0; r < 8; ++r) {         // load tile: 2048 float4 chunks
        int id = t + 256 * r;
        int c = id >> 4, q4 = id & 15;
        *(float4*)(xt + c * 64 + q4 * 4) =
            *(const float4*)(x + (size_t)c * P_TOT + p0 + q4 * 4);
    }
    __syncthreads();
    int pp = t & 63, part = t >> 6;
    float sum = 0.f, ssq = 0.f;
    for (int ci = 0; ci < 32; ++ci) {
        float v = xt[(part * 32 + ci) * 64 + pp];
        sum += v; ssq += v * v;
    }
    red[part * 64 + pp] = sum;
    red[256 + part * 64 + pp] = ssq;
    __syncthreads();
    if (t < 64) {
        float s = red[t] + red[64 + t] + red[128 + t] + red[192 + t];
        float q = red[256 + t] + red[320 + t] + red[384 + t] + red[448 + t];
        float mean = s * (1.f / CH);
        float var  = q * (1.f / CH) - mean * mean;
        stat[t] = mean;
        stat[64 + t] = 1.f / sqrtf(var + 1e-5f);
    }
    __syncthreads();
    float mean = stat[pp], inv = stat[64 + pp];
    u32 pk[32];
    for (int ci = 0; ci < 32; ++ci) {
        int c = part * 32 + ci;
        float v  = xt[c * 64 + pp];
        float xn = (v - mean) * inv * g[c] + b[c];
        pk[ci] = packhl(xn);
    }
    __syncthreads();                      // all xt reads done; reuse buf as tr
    u32* tr = buf;                        // [pp][c] stride 131
    for (int ci = 0; ci < 32; ++ci)
        tr[pp * 131 + part * 32 + ci] = pk[ci];
    __syncthreads();
    #pragma unroll
    for (int r = 0; r < 8; ++r) {         // store: 2048 chunks of 16 B
        int id = t + 256 * r;
        int pr = id >> 5, ch = id & 31;
        const u32* srcp = tr + pr * 131 + ch * 4;
        uint4 v4;
        v4.x = srcp[0]; v4.y = srcp[1]; v4.z = srcp[2]; v4.w = srcp[3];
        *(uint4*)(xnT_pk + (size_t)(p0 + pr) * 128 + ch * 4) = v4;
    }
}

// ---- split qkv (first 512 rows) and wout into bf16 hi/lo planes ------------
__global__ __launch_bounds__(256) void k_wsplit(const float* __restrict__ wqkv,
                                                const float* __restrict__ wout,
                                                u16* __restrict__ w_hi,
                                                u16* __restrict__ w_lo,
                                                u16* __restrict__ w2_hi,
                                                u16* __restrict__ w2_lo) {
    int id = blockIdx.x * 256 + threadIdx.x;   // 0..98303
    if (id < 65536) {
        float v = wqkv[id];
        u16 hh = bf16r(v);
        w_hi[id] = hh; w_lo[id] = bf16r(v - bf16f(hh));
    } else {
        int j = id - 65536;                    // 128*256 wout
        float v = wout[j];
        u16 hh = bf16r(v);
        w2_hi[j] = hh; w2_lo[j] = bf16r(v - bf16f(hh));
    }
}

// ---- MFMA qkv GEMM: qk[o][p] = sum_k w[o][k]*xn[k][p], bf16x3 in one sweep --
__global__ __launch_bounds__(256) void k_gemm_qkv(const u32* __restrict__ xnT_pk,
                                                  const u16* __restrict__ w_hi,
                                                  const u16* __restrict__ w_lo,
                                                  float* __restrict__ qk) {
    __shared__ u16 a_hi[128 * 64], a_lo[128 * 64];
    __shared__ u16 b_hi[128 * 64], b_lo[128 * 64];
    int t    = threadIdx.x;
    int lane = t & 63, wave = t >> 6;
    int wp = wave & 1, wo = wave >> 1;
    int m = lane & 15, quad = lane >> 4;
    int p0 = blockIdx.x * 128;
    int o0 = blockIdx.y * 128;
    f32x4 acc[4][4] = {};
    for (int k0 = 0; k0 < 128; k0 += 64) {
        __syncthreads();
        #pragma unroll
        for (int r = 0; r < 4; ++r) {      // 1024 granules: row=id>>3, g=id&7
            int id  = t + 256 * r;
            int row = id >> 3, gg = id & 7;
            int go  = (gg ^ (row & 7)) * 8;
            const u32* src = xnT_pk + (size_t)(p0 + row) * 128 + k0 + gg * 8;
            u32 pkk[8];
            *(uint4*)pkk       = *(const uint4*)src;
            *(uint4*)(pkk + 4) = *(const uint4*)(src + 4);
            u32 hi4[4], lo4[4];
            #pragma unroll
            for (int e = 0; e < 4; ++e) {
                hi4[e] = __builtin_amdgcn_perm(pkk[2*e+1], pkk[2*e], 0x05040100);
                lo4[e] = __builtin_amdgcn_perm(pkk[2*e+1], pkk[2*e], 0x07060302);
            }
            *(uint4*)(a_hi + row * 64 + go) = *(uint4*)hi4;
            *(uint4*)(a_lo + row * 64 + go) = *(uint4*)lo4;
            *(uint4*)(b_hi + row * 64 + go) =
                *(const uint4*)(w_hi + (size_t)(o0 + row) * 128 + k0 + gg * 8);
            *(uint4*)(b_lo + row * 64 + go) =
                *(const uint4*)(w_lo + (size_t)(o0 + row) * 128 + k0 + gg * 8);
        }
        __syncthreads();
        #pragma unroll
        for (int ks = 0; ks < 2; ++ks) {
            frag8 ah[4], al[4], bh[4], bl[4];
            #pragma unroll
            for (int i = 0; i < 4; ++i) {
                int row = wp * 64 + i * 16 + m;
                int gg  = (ks * 4 + quad) ^ (row & 7);
                ah[i] = *(const frag8*)(a_hi + row * 64 + gg * 8);
                al[i] = *(const frag8*)(a_lo + row * 64 + gg * 8);
            }
            #pragma unroll
            for (int j = 0; j < 4; ++j) {
                int row = wo * 64 + j * 16 + m;
                int gg  = (ks * 4 + quad) ^ (row & 7);
                bh[j] = *(const frag8*)(b_hi + row * 64 + gg * 8);
                bl[j] = *(const frag8*)(b_lo + row * 64 + gg * 8);
            }
            #pragma unroll
            for (int i = 0; i < 4; ++i)
                #pragma unroll
                for (int j = 0; j < 4; ++j) {
                    acc[i][j] = __builtin_amdgcn_mfma_f32_16x16x32_bf16(ah[i], bh[j], acc[i][j], 0, 0, 0);
                    acc[i][j] = __builtin_amdgcn_mfma_f32_16x16x32_bf16(ah[i], bl[j], acc[i][j], 0, 0, 0);
                    acc[i][j] = __builtin_amdgcn_mfma_f32_16x16x32_bf16(al[i], bh[j], acc[i][j], 0, 0, 0);
                }
        }
    }
    #pragma unroll
    for (int i = 0; i < 4; ++i) {
        int p = p0 + wp * 64 + i * 16 + quad * 4;
        #pragma unroll
        for (int j = 0; j < 4; ++j) {
            int o = o0 + wo * 64 + j * 16 + m;
            float4 v;
            v.x = acc[i][j][0]; v.y = acc[i][j][1];
            v.z = acc[i][j][2]; v.w = acc[i][j][3];
            *(float4*)(qk + (size_t)o * P_TOT + p) = v;
        }
    }
}

// ------- l2-normalize q,k in place; additionally emit qT bf16 [h][p][32] -----
__global__ __launch_bounds__(256) void k_norm(float* __restrict__ qk,
                                              u16* __restrict__ qT) {
    int p = blockIdx.x * 256 + threadIdx.x;
    for (int grp = 0; grp < 16; ++grp) {
        float v[32]; float ssq = 0.f;
        #pragma unroll
        for (int c = 0; c < 32; ++c) {
            v[c] = qk[(grp * 32 + c) * P_TOT + p];
            ssq += v[c] * v[c];
        }
        float n  = sqrtf(ssq);
        float sc = 1.f / fmaxf(n, 1e-12f);
        #pragma unroll
        for (int c = 0; c < 32; ++c) {
            v[c] *= sc;
            qk[(grp * 32 + c) * P_TOT + p] = v[c];
        }
        if (grp < 8) {
            u16 row[32];
            #pragma unroll
            for (int c = 0; c < 32; ++c) row[c] = bf16r(v[c]);
            uint4* q4 = (uint4*)(qT + ((size_t)grp * P_TOT + p) * 32);
            q4[0] = *(uint4*)row; q4[1] = *(uint4*)(row + 8);
            q4[2] = *(uint4*)(row + 16); q4[3] = *(uint4*)(row + 24);
        }
    }
}

// ---------------- probes: per (row o, d): total, per-h sums, per-w sums ------
__global__ __launch_bounds__(256) void k_probe(const float* __restrict__ qk,
                                               float* __restrict__ pd,
                                               float* __restrict__ pdh,
                                               float* __restrict__ pdw) {
    int o = blockIdx.x;   // 0..511
    int d = blockIdx.y;   // 0..15
    int t = threadIdx.x;
    __shared__ float ph2[64 * 65];
    __shared__ float pwl[256];
    for (int i = t; i < 64 * 65; i += 256) ph2[i] = 0.f;
    __syncthreads();
    const float* src = qk + o * P_TOT + d * 4096;
    int col = t & 63;
    int tg  = t >> 6;
    float wsum = 0.f;
    #pragma unroll
    for (int r = 0; r < 16; ++r) {
        int i = t + 256 * r;
        float val = fabsf(src[i]);
        wsum += val;
        int h = 4 * r + tg;
        ph2[h * 65 + col] += val;
    }
    pwl[t] = wsum;
    __syncthreads();
    if (t < 64) {
        float s = 0.f;
        for (int cc = 0; cc < 64; ++cc) s += ph2[t * 65 + cc];
        pdh[(o * 16 + d) * 64 + t] = s;
        ph2[t * 65 + 64] = s;
    } else if (t < 128) {
        int w = t - 64;
        float s = 0.f;
        for (int g2 = 0; g2 < 4; ++g2) s += pwl[g2 * 64 + w];
        pdw[(o * 16 + d) * 64 + w] = s;
    }
    __syncthreads();
    if (t == 0) {
        float s = 0.f;
        for (int h = 0; h < 64; ++h) s += ph2[h * 65 + 64];
        pd[o * 16 + d] = s;
    }
}

// ---- reduce probes over d: qph[o][t]=sum_d pdh, qpw[o][t]=sum_d pdw --------
__global__ __launch_bounds__(64) void k_psum(const float* __restrict__ pdh,
                                             const float* __restrict__ pdw,
                                             float* __restrict__ qph,
                                             float* __restrict__ qpw) {
    int o = blockIdx.x, t = threadIdx.x;
    float sh = 0.f, sw = 0.f;
    #pragma unroll
    for (int d = 0; d < 16; ++d) {
        sh += pdh[(o * 16 + d) * 64 + t];
        sw += pdw[(o * 16 + d) * 64 + t];
    }
    qph[o * 64 + t] = sh;
    qpw[o * 64 + t] = sw;
}

// ---------------- top-k kernels ----------------
__global__ __launch_bounds__(64) void k_topk_d(const float* __restrict__ pd,
                                               int* __restrict__ idx_d) {
    int h = blockIdx.x, t = threadIdx.x;
    __shared__ float sc[16];
    if (t < 16) {
        float s = 0.f;
        for (int c = 0; c < 32; ++c)
            s += pd[(h * 32 + c) * 16 + t] * pd[(256 + h * 32 + c) * 16 + t];
        sc[t] = s;
    }
    __syncthreads();
    if (t == 0) {
        bool used[16] = {};
        for (int r = 0; r < KD; ++r) {
            int best = 0; float bv = -1e30f;
            for (int i = 0; i < 16; ++i)
                if (!used[i] && sc[i] > bv) { bv = sc[i]; best = i; }
            used[best] = true;
            idx_d[h * KD + r] = best;
        }
    }
}

__global__ __launch_bounds__(256) void k_topk_h(const float* __restrict__ qph,
                                                const float* __restrict__ pdh,
                                                const int* __restrict__ idx_d,
                                                int* __restrict__ idx_h) {
    int h = blockIdx.x, t = threadIdx.x;
    int tq = t & 63, cg = t >> 6;
    __shared__ float sc2[4][64];
    __shared__ float sc[64];
    int ds[KD];
    #pragma unroll
    for (int i = 0; i < KD; ++i) ds[i] = idx_d[h * KD + i];
    float partial = 0.f;
    for (int ci = 0; ci < 8; ++ci) {
        int c  = cg * 8 + ci;
        int oq = h * 32 + c, ok = 256 + h * 32 + c;
        float qp = qph[oq * 64 + tq];
        float kp = 0.f;
        #pragma unroll
        for (int i = 0; i < KD; ++i) kp += pdh[(ok * 16 + ds[i]) * 64 + tq];
        partial += qp * kp;
    }
    sc2[cg][tq] = partial;
    __syncthreads();
    if (t < 64) sc[t] = sc2[0][t] + sc2[1][t] + sc2[2][t] + sc2[3][t];
    __syncthreads();
    if (t == 0) {
        bool used[64] = {};
        for (int r = 0; r < KH; ++r) {
            int best = 0; float bv = -1e30f;
            for (int i = 0; i < 64; ++i)
                if (!used[i] && sc[i] > bv) { bv = sc[i]; best = i; }
            used[best] = true;
            idx_h[h * KH + r] = best;
        }
    }
}

__global__ __launch_bounds__(64) void k_probe_w(const float* __restrict__ qk,
                                                const int* __restrict__ idx_d,
                                                const int* __restrict__ idx_h,
                                                float* __restrict__ kpw) {
    int o2 = blockIdx.x;
    int w  = threadIdx.x;
    int h  = o2 >> 5;
    const float* src = qk + (256 + o2) * P_TOT;
    float s = 0.f;
    for (int i = 0; i < KD; ++i) {
        int pb = idx_d[h * KD + i] * 4096;
        for (int j = 0; j < KH; ++j)
            s += fabsf(src[pb + idx_h[h * KH + j] * 64 + w]);
    }
    kpw[o2 * 64 + w] = s;
}

__global__ __launch_bounds__(256) void k_topk_w(const float* __restrict__ qpw,
                                                const float* __restrict__ kpw,
                                                int* __restrict__ idx_w) {
    int h = blockIdx.x, t = threadIdx.x;
    int tq = t & 63, cg = t >> 6;
    __shared__ float sc2[4][64];
    __shared__ float sc[64];
    float partial = 0.f;
    for (int ci = 0; ci < 8; ++ci) {
        int c  = cg * 8 + ci;
        int oq = h * 32 + c;
        partial += qpw[oq * 64 + tq] * kpw[(h * 32 + c) * 64 + tq];
    }
    sc2[cg][tq] = partial;
    __syncthreads();
    if (t < 64) sc[t] = sc2[0][t] + sc2[1][t] + sc2[2][t] + sc2[3][t];
    __syncthreads();
    if (t == 0) {
        bool used[64] = {};
        for (int r = 0; r < KW; ++r) {
            int best = 0; float bv = -1e30f;
            for (int i = 0; i < 64; ++i)
                if (!used[i] && sc[i] > bv) { bv = sc[i]; best = i; }
            used[best] = true;
            idx_w[h * KW + r] = best;
        }
    }
}

// ------- gather pruned k (bf16 [h][j][32]) + recompute v (bf16 [h][c][256]) ---
__global__ __launch_bounds__(64) void k_gather(const float* __restrict__ qk,
                                               const u32* __restrict__ xnT_pk,
                                               const float* __restrict__ wqkv,
                                               const int* __restrict__ idx_d,
                                               const int* __restrict__ idx_h,
                                               const int* __restrict__ idx_w,
                                               u16* __restrict__ kb,
                                               u16* __restrict__ vT) {
    int h  = blockIdx.x;          // 0..7
    int jb = blockIdx.y;          // 0..127
    int t  = threadIdx.x;         // 0..63
    int j  = jb * 2 + (t >> 5);
    int c  = t & 31;
    int di = j >> 6, hi = (j >> 3) & 7, wi = j & 7;
    int p  = idx_d[h * KD + di] * 4096 + idx_h[h * KH + hi] * 64 + idx_w[h * KW + wi];
    kb[(h * NJ + j) * 32 + c] = bf16r(qk[(256 + h * 32 + c) * P_TOT + p]);
    const float* wr = wqkv + (512 + h * 32 + c) * CH;
    const u32* xp = xnT_pk + (size_t)p * 128;
    float acc = 0.f;
    for (int cc = 0; cc < CH; ++cc) {
        u32 pk = xp[cc];
        float v = __uint_as_float(pk << 16) + __uint_as_float(pk & 0xffff0000u);
        acc += wr[cc] * v;
    }
    vT[((size_t)h * 32 + c) * NJ + j] = bf16r(acc);
}

// ------- MFMA flash attention: one wave = 16 queries ------------------------
// sPw is WAVE-PRIVATE: no __syncthreads needed (wave-internal LDS ordering via
// lgkmcnt). P packed to bf16 by truncation (1 v_perm per pair) and stored as
// uint2 (ds_write_b64, 2 lanes/bank = conflict-free). PV uses 4 independent
// MFMA chains for ILP. Output written packed (bf16 hi|lo u32), scrambled
// reshape layout (see R2 note).
__global__ __launch_bounds__(256) void k_attn(const u16* __restrict__ qT,
                                              const u16* __restrict__ kb,
                                              const u16* __restrict__ vT,
                                              u32* __restrict__ attn_pk) {
    __shared__ u16 sP[4 * 16 * 264];
    int h    = blockIdx.x >> 10;
    int pb   = blockIdx.x & 1023;
    int wave = threadIdx.x >> 6;
    int lane = threadIdx.x & 63;
    int m    = lane & 15;
    int quad = lane >> 4;
    u16* sPw = sP + wave * (16 * 264);

    int q0 = pb * 64 + wave * 16;
    int p  = q0 + m;

    frag8 bq = *(const frag8*)(qT + ((size_t)h * P_TOT + p) * 32 + quad * 8);
    const u16* kbase = kb + (size_t)h * NJ * 32;

    f32x4 zero = {0.f, 0.f, 0.f, 0.f};
    float den = 0.f;
    #pragma unroll
    for (int t = 0; t < 16; ++t) {
        frag8 ak = *(const frag8*)(kbase + (t * 16 + m) * 32 + quad * 8);
        f32x4 st = __builtin_amdgcn_mfma_f32_16x16x32_bf16(ak, bq, zero, 0, 0, 0);
        float e0 = __expf(st[0]);
        float e1 = __expf(st[1]);
        float e2 = __expf(st[2]);
        float e3 = __expf(st[3]);
        den += (e0 + e1) + (e2 + e3);
        // truncate-pack two bf16 per v_perm (sel: bytes 2,3 of each float)
        uint2 pr;
        pr.x = __builtin_amdgcn_perm(__float_as_uint(e1), __float_as_uint(e0), 0x07060302);
        pr.y = __builtin_amdgcn_perm(__float_as_uint(e3), __float_as_uint(e2), 0x07060302);
        *(uint2*)(sPw + m * 264 + t * 16 + quad * 4) = pr;
    }
    den += __shfl_xor(den, 16, 64);
    den += __shfl_xor(den, 32, 64);
    // no __syncthreads: sPw is private to this wave

    const u16* vbase = vT + (size_t)h * 32 * NJ;
    f32x4 a0e = zero, a0o = zero, a1e = zero, a1o = zero;
    #pragma unroll
    for (int jc = 0; jc < 8; jc += 2) {
        frag8 bp0  = *(const frag8*)(sPw + m * 264 + jc * 32 + quad * 8);
        frag8 bp1  = *(const frag8*)(sPw + m * 264 + (jc + 1) * 32 + quad * 8);
        frag8 av00 = *(const frag8*)(vbase + (size_t)m * NJ + jc * 32 + quad * 8);
        frag8 av01 = *(const frag8*)(vbase + (size_t)m * NJ + (jc + 1) * 32 + quad * 8);
        frag8 av10 = *(const frag8*)(vbase + (size_t)(16 + m) * NJ + jc * 32 + quad * 8);
        frag8 av11 = *(const frag8*)(vbase + (size_t)(16 + m) * NJ + (jc + 1) * 32 + quad * 8);
        a0e = __builtin_amdgcn_mfma_f32_16x16x32_bf16(av00, bp0, a0e, 0, 0, 0);
        a0o = __builtin_amdgcn_mfma_f32_16x16x32_bf16(av01, bp1, a0o, 0, 0, 0);
        a1e = __builtin_amdgcn_mfma_f32_16x16x32_bf16(av10, bp0, a1e, 0, 0, 0);
        a1o = __builtin_amdgcn_mfma_f32_16x16x32_bf16(av11, bp1, a1o, 0, 0, 0);
    }
    f32x4 acc0 = a0e + a0o;
    f32x4 acc1 = a1e + a1o;
    float inv = 1.f / den;
    size_t base = ((size_t)(h * 32 + (p >> 11))) * P_TOT + (size_t)(p & 2047) * 32;
    uint4 o0, o1;
    o0.x = packhl(acc0[0] * inv); o0.y = packhl(acc0[1] * inv);
    o0.z = packhl(acc0[2] * inv); o0.w = packhl(acc0[3] * inv);
    o1.x = packhl(acc1[0] * inv); o1.y = packhl(acc1[1] * inv);
    o1.z = packhl(acc1[2] * inv); o1.w = packhl(acc1[3] * inv);
    *(uint4*)(attn_pk + base + quad * 4)      = o0;
    *(uint4*)(attn_pk + base + 16 + quad * 4) = o1;
}

// ---- MFMA out-proj: out[o][q] = sum_k wout[o][k]*attn[k][q] + bias ---------
__global__ __launch_bounds__(256) void k_gemm_out(const u32* __restrict__ attn_pk,
                                                  const u16* __restrict__ w2_hi,
                                                  const u16* __restrict__ w2_lo,
                                                  const float* __restrict__ bout,
                                                  float* __restrict__ out) {
    __shared__ u16 a_hi[128 * 64], a_lo[128 * 64];   // [q'][k'] swizzled
    __shared__ u16 b_hi[128 * 64], b_lo[128 * 64];   // [o][k'] swizzled
    int t    = threadIdx.x;
    int lane = t & 63, wave = t >> 6;
    int wq = wave & 1, wo = wave >> 1;
    int m = lane & 15, quad = lane >> 4;
    int q0 = blockIdx.x * 128;
    f32x4 acc[4][4] = {};
    for (int k0 = 0; k0 < 256; k0 += 64) {
        __syncthreads();
        #pragma unroll
        for (int r = 0; r < 4; ++r) {      // A: transpose attn[k][q] -> [q][k]
            int id = t + 256 * r;
            int qq = id & 127, gsel = id >> 7;
            u32 pkk[8];
            #pragma unroll
            for (int e = 0; e < 8; ++e)
                pkk[e] = attn_pk[(size_t)(k0 + gsel * 8 + e) * P_TOT + q0 + qq];
            u32 hi4[4], lo4[4];
            #pragma unroll
            for (int e = 0; e < 4; ++e) {
                hi4[e] = __builtin_amdgcn_perm(pkk[2*e+1], pkk[2*e], 0x05040100);
                lo4[e] = __builtin_amdgcn_perm(pkk[2*e+1], pkk[2*e], 0x07060302);
            }
            int go = (gsel ^ (qq & 7)) * 8;
            *(uint4*)(a_hi + qq * 64 + go) = *(uint4*)hi4;
            *(uint4*)(a_lo + qq * 64 + go) = *(uint4*)lo4;
        }
        #pragma unroll
        for (int r = 0; r < 4; ++r) {      // B: wout planes rows 0..127
            int id  = t + 256 * r;
            int row = id >> 3, gg = id & 7;
            int go  = (gg ^ (row & 7)) * 8;
            *(uint4*)(b_hi + row * 64 + go) =
                *(const uint4*)(w2_hi + (size_t)row * 256 + k0 + gg * 8);
            *(uint4*)(b_lo + row * 64 + go) =
                *(const uint4*)(w2_lo + (size_t)row * 256 + k0 + gg * 8);
        }
        __syncthreads();
        #pragma unroll
        for (int ks = 0; ks < 2; ++ks) {
            frag8 ah[4], al[4], bh[4], bl[4];
            #pragma unroll
            for (int i = 0; i < 4; ++i) {
                int row = wq * 64 + i * 16 + m;
                int gg  = (ks * 4 + quad) ^ (row & 7);
                ah[i] = *(const frag8*)(a_hi + row * 64 + gg * 8);
                al[i] = *(const frag8*)(a_lo + row * 64 + gg * 8);
            }
            #pragma unroll
            for (int j = 0; j < 4; ++j) {
                int row = wo * 64 + j * 16 + m;
                int gg  = (ks * 4 + quad) ^ (row & 7);
                bh[j] = *(const frag8*)(b_hi + row * 64 + gg * 8);
                bl[j] = *(const frag8*)(b_lo + row * 64 + gg * 8);
            }
            #pragma unroll
            for (int i = 0; i < 4; ++i)
                #pragma unroll
                for (int j = 0; j < 4; ++j) {
                    acc[i][j] = __builtin_amdgcn_mfma_f32_16x16x32_bf16(ah[i], bh[j], acc[i][j], 0, 0, 0);
                    acc[i][j] = __builtin_amdgcn_mfma_f32_16x16x32_bf16(ah[i], bl[j], acc[i][j], 0, 0, 0);
                    acc[i][j] = __builtin_amdgcn_mfma_f32_16x16x32_bf16(al[i], bh[j], acc[i][j], 0, 0, 0);
                }
        }
    }
    #pragma unroll
    for (int j = 0; j < 4; ++j) {
        int o = wo * 64 + j * 16 + m;
        float bv = bout[o];
        #pragma unroll
        for (int i = 0; i < 4; ++i) {
            int q = q0 + wq * 64 + i * 16 + quad * 4;
            float4 v;
            v.x = acc[i][j][0] + bv; v.y = acc[i][j][1] + bv;
            v.z = acc[i][j][2] + bv; v.w = acc[i][j][3] + bv;
            *(float4*)(out + (size_t)o * P_TOT + q) = v;
        }
    }
}

extern "C" void kernel_launch(void* const* d_in, const int* in_sizes, int n_in,
                              void* d_out, int out_size, void* d_ws, size_t ws_size,
                              hipStream_t stream) {
    const float* x    = (const float*)d_in[0];
    const float* g    = (const float*)d_in[1];
    const float* b    = (const float*)d_in[2];
    const float* wqkv = (const float*)d_in[3];
    const float* wout = (const float*)d_in[4];
    const float* bout = (const float*)d_in[5];
    float* out = (float*)d_out;
    float* ws  = (float*)d_ws;

    // ws layout:
    u32*   xnT_pk = (u32*)ws;               // 128*65536 u32 (packed bf16 hi|lo)
    float* qk   = ws + 8388608;             // 512*65536 fp32 (q rows 0..255, k 256..511)
    u32*   attn_pk = (u32*)(qk + 256 * P_TOT);  // overlays k rows after gather
    float* aux  = ws + 41943040;
    float* pd    = aux;                     // 8192
    float* pdh   = pd + 8192;               // 524288
    float* pdw   = pdh + 524288;            // 524288
    float* kpw   = pdw + 524288;            // 16384
    float* qph   = kpw + 16384;             // 32768
    float* qpw   = qph + 32768;             // 32768
    int*   idx_d = (int*)(qpw + 32768);     // 32
    int*   idx_h = idx_d + 32;              // 64
    int*   idx_w = idx_h + 64;              // 64
    u16*   kb    = (u16*)(idx_w + 64);      // 8*256*32 bf16
    u16*   vT    = kb + 8 * NJ * 32;        // 8*32*256 bf16
    u16*   qT    = vT + 8 * 32 * NJ;        // 8*65536*32 bf16 (33.5 MB)
    u16*   w_hi  = qT + (size_t)8 * P_TOT * 32;  // 512*128
    u16*   w_lo  = w_hi + 512 * 128;             // 512*128
    u16*   w2_hi = w_lo + 512 * 128;             // 128*256
    u16*   w2_lo = w2_hi + 128 * 256;            // 128*256

    k_ln<<<1024, 256, 0, stream>>>(x, g, b, xnT_pk);
    k_wsplit<<<384, 256, 0, stream>>>(wqkv, wout, w_hi, w_lo, w2_hi, w2_lo);
    k_gemm_qkv<<<dim3(512, 4), 256, 0, stream>>>(xnT_pk, w_hi, w_lo, qk);
    k_norm<<<256, 256, 0, stream>>>(qk, qT);
    k_probe<<<dim3(512, 16), 256, 0, stream>>>(qk, pd, pdh, pdw);
    k_psum<<<512, 64, 0, stream>>>(pdh, pdw, qph, qpw);
    k_topk_d<<<8, 64, 0, stream>>>(pd, idx_d);
    k_topk_h<<<8, 256, 0, stream>>>(qph, pdh, idx_d, idx_h);
    k_probe_w<<<256, 64, 0, stream>>>(qk, idx_d, idx_h, kpw);
    k_topk_w<<<8, 256, 0, stream>>>(qpw, kpw, idx_w);
    k_gather<<<dim3(8, 128), 64, 0, stream>>>(qk, xnT_pk, wqkv,
                                              idx_d, idx_h, idx_w, kb, vT);
    k_attn<<<8192, 256, 0, stream>>>(qT, kb, vT, attn_pk);
    k_gemm_out<<<512, 256, 0, stream>>>(attn_pk, w2_hi, w2_lo, bout, out);
}